// Round 3
// baseline (1308.949 us; speedup 1.0000x reference)
//
#include <hip/hip_runtime.h>

#define DMODEL 128
#define NEG_SLOPE 0.01f
#define NPB 64              // nodes per bucket
#define NBK_MAX 1600        // max buckets supported by LDS arrays (N <= 102400)
#define CPAD 16             // counter padding (ints) -> one counter per 64B line

typedef unsigned int uint;
typedef unsigned short ushort_t;

// round-to-nearest-even f32 -> bf16
__device__ inline ushort_t f2bf(float f) {
    uint u = __float_as_uint(f);
    u += 0x7FFFu + ((u >> 16) & 1u);
    return (ushort_t)(u >> 16);
}

// ---------------------------------------------------------------------------
// GEMM: H(bf16) = X @ W   (N x 128) @ (128 x 128)
// ---------------------------------------------------------------------------
__global__ __launch_bounds__(256) void k_gemm(const float* __restrict__ X,
                                              const float* __restrict__ W,
                                              ushort_t* __restrict__ H, int N) {
    __shared__ float Xs[64][128];
    __shared__ float Ws[128][64];
    const int b = blockIdx.x;
    const int rb = b >> 1, cb = b & 1;
    const int row0 = rb * 64, col0 = cb * 64;
    const int t = threadIdx.x;

#pragma unroll
    for (int i = 0; i < 8; ++i) {
        int flat = (t + i * 256) * 4;
        int r = flat >> 7;
        int k = flat & 127;
        float4 v = make_float4(0.f, 0.f, 0.f, 0.f);
        if (row0 + r < N) v = *(const float4*)(X + (size_t)(row0 + r) * DMODEL + k);
        *(float4*)(&Xs[r][k]) = v;
    }
#pragma unroll
    for (int i = 0; i < 8; ++i) {
        int flat = (t + i * 256) * 4;
        int k = flat >> 6;
        int c = flat & 63;
        *(float4*)(&Ws[k][c]) = *(const float4*)(W + (size_t)k * DMODEL + col0 + c);
    }
    __syncthreads();

    const int tx = t & 15, ty = t >> 4;
    float acc[4][4] = {};
    for (int k4 = 0; k4 < 128; k4 += 4) {
        float4 xv[4];
#pragma unroll
        for (int i = 0; i < 4; ++i) xv[i] = *(const float4*)(&Xs[ty * 4 + i][k4]);
#pragma unroll
        for (int kk = 0; kk < 4; ++kk) {
            float4 wv = *(const float4*)(&Ws[k4 + kk][tx * 4]);
#pragma unroll
            for (int i = 0; i < 4; ++i) {
                float x = ((const float*)&xv[i])[kk];
                acc[i][0] += x * wv.x;
                acc[i][1] += x * wv.y;
                acc[i][2] += x * wv.z;
                acc[i][3] += x * wv.w;
            }
        }
    }
#pragma unroll
    for (int i = 0; i < 4; ++i) {
        int r = row0 + ty * 4 + i;
        if (r < N) {
            ushort4 o;
            o.x = f2bf(acc[i][0]);
            o.y = f2bf(acc[i][1]);
            o.z = f2bf(acc[i][2]);
            o.w = f2bf(acc[i][3]);
            *(ushort4*)(H + (size_t)r * DMODEL + col0 + tx * 4) = o;
        }
    }
}

// ---------------------------------------------------------------------------
// zero padded global counters
// ---------------------------------------------------------------------------
__global__ __launch_bounds__(256) void k_zero(int* __restrict__ p, int n) {
    int i = blockIdx.x * 256 + threadIdx.x;
    if (i < n) p[i] = 0;
}

// ---------------------------------------------------------------------------
// Phase A: bucket histogram (LDS-staged)
// ---------------------------------------------------------------------------
__global__ __launch_bounds__(256) void k_bhist(const int* __restrict__ er,
                                               int* __restrict__ gcnt_p,
                                               int E, int NBK, int chunk) {
    __shared__ int lh[NBK_MAX];
    const int t = threadIdx.x;
    for (int k = t; k < NBK; k += 256) lh[k] = 0;
    __syncthreads();
    const int s0 = blockIdx.x * chunk;
    const int s1 = min(E, s0 + chunk);
    for (int i = s0 + t; i < s1; i += 256)
        atomicAdd(&lh[er[i] >> 6], 1);
    __syncthreads();
    for (int k = t; k < NBK; k += 256) {
        int c = lh[k];
        if (c) atomicAdd(&gcnt_p[k * CPAD], c);
    }
}

// ---------------------------------------------------------------------------
// Phase B: exclusive scan of NBK bucket counts -> bptr[NBK+1], gcur_p
// single block, 256 threads
// ---------------------------------------------------------------------------
__global__ __launch_bounds__(256) void k_bscan(const int* __restrict__ gcnt_p,
                                               int* __restrict__ bptr,
                                               int* __restrict__ gcur_p, int NBK) {
    __shared__ int ps[256];
    const int t = threadIdx.x;
    const int SEG = (NBK + 255) >> 8;     // <= 16 for NBK <= 4096
    const int base = t * SEG;
    int cnt[16];
    int s = 0;
    for (int i = 0; i < SEG; ++i) {
        int idx = base + i;
        int c = (idx < NBK) ? gcnt_p[idx * CPAD] : 0;
        cnt[i] = c;
        s += c;
    }
    ps[t] = s;
    __syncthreads();
    for (int o = 1; o < 256; o <<= 1) {
        int x = (t >= o) ? ps[t - o] : 0;
        __syncthreads();
        ps[t] += x;
        __syncthreads();
    }
    int run = (t > 0) ? ps[t - 1] : 0;
    for (int i = 0; i < SEG; ++i) {
        int idx = base + i;
        if (idx < NBK) {
            bptr[idx] = run;
            gcur_p[idx * CPAD] = run;
            run += cnt[i];
        }
    }
    if (t == 255) bptr[NBK] = ps[255];
}

// ---------------------------------------------------------------------------
// Phase C: scatter edges into bucket-grouped array with block-level
// range reservation (coalesced-ish writes).
// entry: x = (row_local << 17) | col ; y = f32 edge value
// ---------------------------------------------------------------------------
__global__ __launch_bounds__(256) void k_bscat(const int* __restrict__ er,
                                               const int* __restrict__ ec,
                                               const float* __restrict__ ev,
                                               int* __restrict__ gcur_p,
                                               int2* __restrict__ packed,
                                               int E, int NBK, int chunk) {
    __shared__ int lh[NBK_MAX];
    __shared__ int lb[NBK_MAX];
    const int t = threadIdx.x;
    for (int k = t; k < NBK; k += 256) lh[k] = 0;
    __syncthreads();
    const int s0 = blockIdx.x * chunk;
    const int s1 = min(E, s0 + chunk);
    for (int i = s0 + t; i < s1; i += 256)
        atomicAdd(&lh[er[i] >> 6], 1);
    __syncthreads();
    for (int k = t; k < NBK; k += 256) {
        int c = lh[k];
        lb[k] = c ? atomicAdd(&gcur_p[k * CPAD], c) : 0;
        lh[k] = 0;   // reuse as local cursor
    }
    __syncthreads();
    for (int i = s0 + t; i < s1; i += 256) {
        int r = er[i];
        int bkt = r >> 6;
        int rl = r & 63;
        int slot = atomicAdd(&lh[bkt], 1);
        packed[lb[bkt] + slot] = make_int2((rl << 17) | ec[i], __float_as_int(ev[i]));
    }
}

// ---------------------------------------------------------------------------
// Aggregate: one block per 64-node bucket; f32 accumulators in LDS
// (split X/Y arrays -> stride-1 per lane, conflict-free). Wave-parallel
// edge processing: 64-entry lane prefetch + readlane broadcast, 8-unrolled.
// ---------------------------------------------------------------------------
__global__ __launch_bounds__(256) void k_bagg(const uint* __restrict__ Hb,
                                              const int* __restrict__ bptr,
                                              const int2* __restrict__ packed,
                                              const float* __restrict__ bias,
                                              float* __restrict__ out, int N) {
    __shared__ float accX[NPB][64];
    __shared__ float accY[NPB][64];
    const int t = threadIdx.x;
    const int wid = t >> 6, lane = t & 63;
    const int b = blockIdx.x;

    // zero accumulators: 32KB / 256 thr = 32 floats each
#pragma unroll
    for (int i = 0; i < 4; ++i) {
        ((float4*)accX)[t + i * 256] = make_float4(0.f, 0.f, 0.f, 0.f);
        ((float4*)accY)[t + i * 256] = make_float4(0.f, 0.f, 0.f, 0.f);
    }
    __syncthreads();

    const int s = bptr[b], e = bptr[b + 1];
    for (int base = s + wid * 64; base < e; base += 256) {
        const int m = min(64, e - base);
        int2 p = make_int2(0, 0);
        if (lane < m) p = packed[base + lane];
        int j = 0;
        for (; j + 8 <= m; j += 8) {
#pragma unroll
            for (int q = 0; q < 8; ++q) {
                const uint xv = (uint)__builtin_amdgcn_readlane(p.x, j + q);
                const float v = __int_as_float(__builtin_amdgcn_readlane(p.y, j + q));
                const int col = xv & 0x1FFFF;
                const int rl = xv >> 17;
                const uint u = Hb[(size_t)col * 64 + lane];
                atomicAdd(&accX[rl][lane], v * __uint_as_float(u << 16));
                atomicAdd(&accY[rl][lane], v * __uint_as_float(u & 0xffff0000u));
            }
        }
        for (; j < m; ++j) {
            const uint xv = (uint)__builtin_amdgcn_readlane(p.x, j);
            const float v = __int_as_float(__builtin_amdgcn_readlane(p.y, j));
            const int col = xv & 0x1FFFF;
            const int rl = xv >> 17;
            const uint u = Hb[(size_t)col * 64 + lane];
            atomicAdd(&accX[rl][lane], v * __uint_as_float(u << 16));
            atomicAdd(&accY[rl][lane], v * __uint_as_float(u & 0xffff0000u));
        }
    }
    __syncthreads();

    // epilogue: wave w -> rows [w*16, w*16+16)
    const float2 bv = ((const float2*)bias)[lane];
#pragma unroll
    for (int i = 0; i < 16; ++i) {
        const int r = wid * 16 + i;
        const int node = b * NPB + r;
        if (node >= N) continue;
        float ox = accX[r][lane] + bv.x;
        float oy = accY[r][lane] + bv.y;
        ox = ox >= 0.f ? ox : NEG_SLOPE * ox;
        oy = oy >= 0.f ? oy : NEG_SLOPE * oy;
        ((float2*)(out + (size_t)node * DMODEL))[lane] = make_float2(ox, oy);
    }
}

// ---------------------------------------------------------------------------
extern "C" void kernel_launch(void* const* d_in, const int* in_sizes, int n_in,
                              void* d_out, int out_size, void* d_ws, size_t ws_size,
                              hipStream_t stream) {
    const float* X    = (const float*)d_in[0];
    const int*   er   = (const int*)d_in[1];
    const int*   ec   = (const int*)d_in[2];
    const float* ev   = (const float*)d_in[3];
    const float* W    = (const float*)d_in[4];
    const float* bias = (const float*)d_in[5];
    float* out = (float*)d_out;

    const int N = in_sizes[0] / DMODEL;
    const int E = in_sizes[1];
    const int NBK = (N + NPB - 1) / NPB;   // 1563 for N=100000 (must be <= NBK_MAX)

    // workspace layout (128B-aligned slabs)
    char* ws = (char*)d_ws;
    size_t off = 0;
    auto alloc = [&](size_t bytes) {
        void* p = ws + off;
        off += (bytes + 127) & ~(size_t)127;
        return p;
    };
    ushort_t* H  = (ushort_t*)alloc((size_t)N * DMODEL * sizeof(ushort_t));
    int* gcnt_p  = (int*)alloc((size_t)NBK * CPAD * sizeof(int));
    int* gcur_p  = (int*)alloc((size_t)NBK * CPAD * sizeof(int));
    int* bptr    = (int*)alloc((size_t)(NBK + 1) * sizeof(int));
    int2* packed = (int2*)alloc((size_t)E * sizeof(int2));
    (void)ws_size;

    // 1) GEMM (f32 in, bf16 out)
    const int gemm_blocks = ((N + 63) / 64) * 2;
    hipLaunchKernelGGL(k_gemm, dim3(gemm_blocks), dim3(256), 0, stream, X, W, H, N);

    // 2) bucket grouping
    const int NBLK = 256;
    const int chunk = (E + NBLK - 1) / NBLK;
    hipLaunchKernelGGL(k_zero,  dim3((NBK * CPAD + 255) / 256), dim3(256), 0, stream,
                       gcnt_p, NBK * CPAD);
    hipLaunchKernelGGL(k_bhist, dim3(NBLK), dim3(256), 0, stream, er, gcnt_p, E, NBK, chunk);
    hipLaunchKernelGGL(k_bscan, dim3(1), dim3(256), 0, stream, gcnt_p, bptr, gcur_p, NBK);
    hipLaunchKernelGGL(k_bscat, dim3(NBLK), dim3(256), 0, stream,
                       er, ec, ev, gcur_p, packed, E, NBK, chunk);

    // 3) bucketed aggregate + bias + leaky-relu
    hipLaunchKernelGGL(k_bagg, dim3(NBK), dim3(256), 0, stream,
                       (const uint*)H, bptr, packed, bias, out, N);
}

// Round 4
// 210.528 us; speedup vs baseline: 6.2175x; 6.2175x over previous
//
#include <hip/hip_runtime.h>

#define DMODEL 128
#define NEG_SLOPE 0.01f
#define NPB 64              // nodes per bucket
#define NBK_MAX 1600        // max buckets supported by LDS arrays (N <= 102400)
#define CPAD 16             // counter padding (ints) -> one counter per 64B line

typedef unsigned int uint;
typedef unsigned short ushort_t;

// round-to-nearest-even f32 -> bf16
__device__ inline ushort_t f2bf(float f) {
    uint u = __float_as_uint(f);
    u += 0x7FFFu + ((u >> 16) & 1u);
    return (ushort_t)(u >> 16);
}

// ---------------------------------------------------------------------------
// GEMM: H(bf16) = X @ W   (N x 128) @ (128 x 128)
// ---------------------------------------------------------------------------
__global__ __launch_bounds__(256) void k_gemm(const float* __restrict__ X,
                                              const float* __restrict__ W,
                                              ushort_t* __restrict__ H, int N) {
    __shared__ float Xs[64][128];
    __shared__ float Ws[128][64];
    const int b = blockIdx.x;
    const int rb = b >> 1, cb = b & 1;
    const int row0 = rb * 64, col0 = cb * 64;
    const int t = threadIdx.x;

#pragma unroll
    for (int i = 0; i < 8; ++i) {
        int flat = (t + i * 256) * 4;
        int r = flat >> 7;
        int k = flat & 127;
        float4 v = make_float4(0.f, 0.f, 0.f, 0.f);
        if (row0 + r < N) v = *(const float4*)(X + (size_t)(row0 + r) * DMODEL + k);
        *(float4*)(&Xs[r][k]) = v;
    }
#pragma unroll
    for (int i = 0; i < 8; ++i) {
        int flat = (t + i * 256) * 4;
        int k = flat >> 6;
        int c = flat & 63;
        *(float4*)(&Ws[k][c]) = *(const float4*)(W + (size_t)k * DMODEL + col0 + c);
    }
    __syncthreads();

    const int tx = t & 15, ty = t >> 4;
    float acc[4][4] = {};
    for (int k4 = 0; k4 < 128; k4 += 4) {
        float4 xv[4];
#pragma unroll
        for (int i = 0; i < 4; ++i) xv[i] = *(const float4*)(&Xs[ty * 4 + i][k4]);
#pragma unroll
        for (int kk = 0; kk < 4; ++kk) {
            float4 wv = *(const float4*)(&Ws[k4 + kk][tx * 4]);
#pragma unroll
            for (int i = 0; i < 4; ++i) {
                float x = ((const float*)&xv[i])[kk];
                acc[i][0] += x * wv.x;
                acc[i][1] += x * wv.y;
                acc[i][2] += x * wv.z;
                acc[i][3] += x * wv.w;
            }
        }
    }
#pragma unroll
    for (int i = 0; i < 4; ++i) {
        int r = row0 + ty * 4 + i;
        if (r < N) {
            ushort4 o;
            o.x = f2bf(acc[i][0]);
            o.y = f2bf(acc[i][1]);
            o.z = f2bf(acc[i][2]);
            o.w = f2bf(acc[i][3]);
            *(ushort4*)(H + (size_t)r * DMODEL + col0 + tx * 4) = o;
        }
    }
}

// ---------------------------------------------------------------------------
__global__ __launch_bounds__(256) void k_zero(int* __restrict__ p, int n) {
    int i = blockIdx.x * 256 + threadIdx.x;
    if (i < n) p[i] = 0;
}

// ---------------------------------------------------------------------------
// Phase A: bucket histogram (LDS-staged)
// ---------------------------------------------------------------------------
__global__ __launch_bounds__(256) void k_bhist(const int* __restrict__ er,
                                               int* __restrict__ gcnt_p,
                                               int E, int NBK, int chunk) {
    __shared__ int lh[NBK_MAX];
    const int t = threadIdx.x;
    for (int k = t; k < NBK; k += 256) lh[k] = 0;
    __syncthreads();
    const int s0 = blockIdx.x * chunk;
    const int s1 = min(E, s0 + chunk);
    for (int i = s0 + t; i < s1; i += 256)
        atomicAdd(&lh[er[i] >> 6], 1);
    __syncthreads();
    for (int k = t; k < NBK; k += 256) {
        int c = lh[k];
        if (c) atomicAdd(&gcnt_p[k * CPAD], c);
    }
}

// ---------------------------------------------------------------------------
// Phase B: exclusive scan of NBK bucket counts -> bptr[NBK+1], gcur_p
// ---------------------------------------------------------------------------
__global__ __launch_bounds__(256) void k_bscan(const int* __restrict__ gcnt_p,
                                               int* __restrict__ bptr,
                                               int* __restrict__ gcur_p, int NBK) {
    __shared__ int ps[256];
    const int t = threadIdx.x;
    const int SEG = (NBK + 255) >> 8;     // <= 16 for NBK <= 4096
    const int base = t * SEG;
    int cnt[16];
    int s = 0;
    for (int i = 0; i < SEG; ++i) {
        int idx = base + i;
        int c = (idx < NBK) ? gcnt_p[idx * CPAD] : 0;
        cnt[i] = c;
        s += c;
    }
    ps[t] = s;
    __syncthreads();
    for (int o = 1; o < 256; o <<= 1) {
        int x = (t >= o) ? ps[t - o] : 0;
        __syncthreads();
        ps[t] += x;
        __syncthreads();
    }
    int run = (t > 0) ? ps[t - 1] : 0;
    for (int i = 0; i < SEG; ++i) {
        int idx = base + i;
        if (idx < NBK) {
            bptr[idx] = run;
            gcur_p[idx * CPAD] = run;
            run += cnt[i];
        }
    }
    if (t == 255) bptr[NBK] = ps[255];
}

// ---------------------------------------------------------------------------
// Phase C: scatter edges into bucket-grouped array with block-level
// range reservation. entry: x = (row_local << 17) | col ; y = f32 edge value
// ---------------------------------------------------------------------------
__global__ __launch_bounds__(256) void k_bscat(const int* __restrict__ er,
                                               const int* __restrict__ ec,
                                               const float* __restrict__ ev,
                                               int* __restrict__ gcur_p,
                                               int2* __restrict__ packed0,
                                               int E, int NBK, int chunk) {
    __shared__ int lh[NBK_MAX];
    __shared__ int lb[NBK_MAX];
    const int t = threadIdx.x;
    for (int k = t; k < NBK; k += 256) lh[k] = 0;
    __syncthreads();
    const int s0 = blockIdx.x * chunk;
    const int s1 = min(E, s0 + chunk);
    for (int i = s0 + t; i < s1; i += 256)
        atomicAdd(&lh[er[i] >> 6], 1);
    __syncthreads();
    for (int k = t; k < NBK; k += 256) {
        int c = lh[k];
        lb[k] = c ? atomicAdd(&gcur_p[k * CPAD], c) : 0;
        lh[k] = 0;   // reuse as local cursor
    }
    __syncthreads();
    for (int i = s0 + t; i < s1; i += 256) {
        int r = er[i];
        int bkt = r >> 6;
        int rl = r & 63;
        int slot = atomicAdd(&lh[bkt], 1);
        packed0[lb[bkt] + slot] = make_int2((rl << 17) | ec[i], __float_as_int(ev[i]));
    }
}

// ---------------------------------------------------------------------------
// Phase D: per-bucket regroup -> exact per-node CSR (packed1, row_ptr, row_end).
// One block per bucket; all writes land in the bucket's ~8KB window.
// ---------------------------------------------------------------------------
__global__ __launch_bounds__(256) void k_regroup(const int2* __restrict__ packed0,
                                                 const int* __restrict__ bptr,
                                                 int2* __restrict__ packed1,
                                                 int* __restrict__ row_ptr,
                                                 int* __restrict__ row_end, int N) {
    __shared__ int lcnt[NPB];
    __shared__ int lpref[NPB];
    __shared__ int lcur[NPB];
    const int t = threadIdx.x;
    const int b = blockIdx.x;
    if (t < NPB) { lcnt[t] = 0; lcur[t] = 0; }
    __syncthreads();
    const int s = bptr[b], e = bptr[b + 1];
    for (int i = s + t; i < e; i += 256)
        atomicAdd(&lcnt[((uint)packed0[i].x) >> 17], 1);
    __syncthreads();
    if (t < NPB) {
        int p = 0;
        for (int k = 0; k < t; ++k) p += lcnt[k];
        lpref[t] = p;
        const int node = b * NPB + t;
        if (node < N) {
            row_ptr[node] = s + p;
            row_end[node] = s + p + lcnt[t];
        }
    }
    __syncthreads();
    for (int i = s + t; i < e; i += 256) {
        int2 en = packed0[i];
        const int rl = ((uint)en.x) >> 17;
        const int pos = s + lpref[rl] + atomicAdd(&lcur[rl], 1);
        packed1[pos] = make_int2(en.x & 0x1FFFF, en.y);
    }
}

// ---------------------------------------------------------------------------
// Aggregate: one wave per dest node; each lane owns 2 bf16 columns of H.
// Edge metadata prefetched lane-parallel, broadcast via readlane, 4-unrolled.
// ---------------------------------------------------------------------------
__global__ __launch_bounds__(256) void k_agg(const uint* __restrict__ Hb,
                                             const int* __restrict__ row_ptr,
                                             const int* __restrict__ row_end,
                                             const int2* __restrict__ packed1,
                                             const float* __restrict__ bias,
                                             float* __restrict__ out, int N) {
    const int wid = threadIdx.x >> 6, lane = threadIdx.x & 63;
    const int n = blockIdx.x * 4 + wid;
    if (n >= N) return;
    const int start = row_ptr[n], end = row_end[n];
    float ax = 0.f, ay = 0.f;
    for (int base = start; base < end; base += 64) {
        const int m = min(64, end - base);
        int2 p = make_int2(0, 0);
        if (lane < m) p = packed1[base + lane];
        int j = 0;
        for (; j + 4 <= m; j += 4) {
#pragma unroll
            for (int q = 0; q < 4; ++q) {
                const int col = __builtin_amdgcn_readlane(p.x, j + q);
                const float v = __int_as_float(__builtin_amdgcn_readlane(p.y, j + q));
                const uint u = Hb[(size_t)col * 64 + lane];
                ax = fmaf(v, __uint_as_float(u << 16), ax);
                ay = fmaf(v, __uint_as_float(u & 0xffff0000u), ay);
            }
        }
        for (; j < m; ++j) {
            const int col = __builtin_amdgcn_readlane(p.x, j);
            const float v = __int_as_float(__builtin_amdgcn_readlane(p.y, j));
            const uint u = Hb[(size_t)col * 64 + lane];
            ax = fmaf(v, __uint_as_float(u << 16), ax);
            ay = fmaf(v, __uint_as_float(u & 0xffff0000u), ay);
        }
    }
    float2 bv = ((const float2*)bias)[lane];
    float ox = ax + bv.x, oy = ay + bv.y;
    ox = ox >= 0.f ? ox : NEG_SLOPE * ox;
    oy = oy >= 0.f ? oy : NEG_SLOPE * oy;
    ((float2*)(out + (size_t)n * DMODEL))[lane] = make_float2(ox, oy);
}

// ---------------------------------------------------------------------------
extern "C" void kernel_launch(void* const* d_in, const int* in_sizes, int n_in,
                              void* d_out, int out_size, void* d_ws, size_t ws_size,
                              hipStream_t stream) {
    const float* X    = (const float*)d_in[0];
    const int*   er   = (const int*)d_in[1];
    const int*   ec   = (const int*)d_in[2];
    const float* ev   = (const float*)d_in[3];
    const float* W    = (const float*)d_in[4];
    const float* bias = (const float*)d_in[5];
    float* out = (float*)d_out;

    const int N = in_sizes[0] / DMODEL;
    const int E = in_sizes[1];
    const int NBK = (N + NPB - 1) / NPB;   // 1563 for N=100000 (<= NBK_MAX)

    // workspace layout (128B-aligned slabs)
    char* ws = (char*)d_ws;
    size_t off = 0;
    auto alloc = [&](size_t bytes) {
        void* p = ws + off;
        off += (bytes + 127) & ~(size_t)127;
        return p;
    };
    ushort_t* H   = (ushort_t*)alloc((size_t)N * DMODEL * sizeof(ushort_t));
    int* gcnt_p   = (int*)alloc((size_t)NBK * CPAD * sizeof(int));
    int* gcur_p   = (int*)alloc((size_t)NBK * CPAD * sizeof(int));
    int* bptr     = (int*)alloc((size_t)(NBK + 1) * sizeof(int));
    int* row_ptr  = (int*)alloc((size_t)N * sizeof(int));
    int* row_end  = (int*)alloc((size_t)N * sizeof(int));
    int2* packed0 = (int2*)alloc((size_t)E * sizeof(int2));
    int2* packed1 = (int2*)alloc((size_t)E * sizeof(int2));
    (void)ws_size;

    // 1) GEMM (f32 in, bf16 out)
    const int gemm_blocks = ((N + 63) / 64) * 2;
    hipLaunchKernelGGL(k_gemm, dim3(gemm_blocks), dim3(256), 0, stream, X, W, H, N);

    // 2) two-level edge grouping
    const int NBLK = 128;                  // ~8-entry runs in k_bscat -> full lines
    const int chunk = (E + NBLK - 1) / NBLK;
    hipLaunchKernelGGL(k_zero,  dim3((NBK * CPAD + 255) / 256), dim3(256), 0, stream,
                       gcnt_p, NBK * CPAD);
    hipLaunchKernelGGL(k_bhist, dim3(NBLK), dim3(256), 0, stream, er, gcnt_p, E, NBK, chunk);
    hipLaunchKernelGGL(k_bscan, dim3(1), dim3(256), 0, stream, gcnt_p, bptr, gcur_p, NBK);
    hipLaunchKernelGGL(k_bscat, dim3(NBLK), dim3(256), 0, stream,
                       er, ec, ev, gcur_p, packed0, E, NBK, chunk);
    hipLaunchKernelGGL(k_regroup, dim3(NBK), dim3(256), 0, stream,
                       packed0, bptr, packed1, row_ptr, row_end, N);

    // 3) gather-aggregate, one wave per node
    hipLaunchKernelGGL(k_agg, dim3((N + 3) / 4), dim3(256), 0, stream,
                       (const uint*)H, row_ptr, row_end, packed1, bias, out, N);
}

// Round 5
// 200.097 us; speedup vs baseline: 6.5416x; 1.0521x over previous
//
#include <hip/hip_runtime.h>

#define DMODEL 128
#define NEG_SLOPE 0.01f
#define NPB 64              // nodes per bucket
#define NBK_MAX 1600        // max buckets supported by LDS arrays (N <= 102400)
#define CPAD 16             // counter padding (ints) -> one counter per 64B line

typedef unsigned int uint;
typedef unsigned short ushort_t;

// round-to-nearest-even f32 -> bf16
__device__ inline ushort_t f2bf(float f) {
    uint u = __float_as_uint(f);
    u += 0x7FFFu + ((u >> 16) & 1u);
    return (ushort_t)(u >> 16);
}

// ---------------------------------------------------------------------------
// GEMM: H(bf16) = X @ W   (N x 128) @ (128 x 128)
// ---------------------------------------------------------------------------
__global__ __launch_bounds__(256) void k_gemm(const float* __restrict__ X,
                                              const float* __restrict__ W,
                                              ushort_t* __restrict__ H, int N) {
    __shared__ float Xs[64][128];
    __shared__ float Ws[128][64];
    const int b = blockIdx.x;
    const int rb = b >> 1, cb = b & 1;
    const int row0 = rb * 64, col0 = cb * 64;
    const int t = threadIdx.x;

#pragma unroll
    for (int i = 0; i < 8; ++i) {
        int flat = (t + i * 256) * 4;
        int r = flat >> 7;
        int k = flat & 127;
        float4 v = make_float4(0.f, 0.f, 0.f, 0.f);
        if (row0 + r < N) v = *(const float4*)(X + (size_t)(row0 + r) * DMODEL + k);
        *(float4*)(&Xs[r][k]) = v;
    }
#pragma unroll
    for (int i = 0; i < 8; ++i) {
        int flat = (t + i * 256) * 4;
        int k = flat >> 6;
        int c = flat & 63;
        *(float4*)(&Ws[k][c]) = *(const float4*)(W + (size_t)k * DMODEL + col0 + c);
    }
    __syncthreads();

    const int tx = t & 15, ty = t >> 4;
    float acc[4][4] = {};
    for (int k4 = 0; k4 < 128; k4 += 4) {
        float4 xv[4];
#pragma unroll
        for (int i = 0; i < 4; ++i) xv[i] = *(const float4*)(&Xs[ty * 4 + i][k4]);
#pragma unroll
        for (int kk = 0; kk < 4; ++kk) {
            float4 wv = *(const float4*)(&Ws[k4 + kk][tx * 4]);
#pragma unroll
            for (int i = 0; i < 4; ++i) {
                float x = ((const float*)&xv[i])[kk];
                acc[i][0] += x * wv.x;
                acc[i][1] += x * wv.y;
                acc[i][2] += x * wv.z;
                acc[i][3] += x * wv.w;
            }
        }
    }
#pragma unroll
    for (int i = 0; i < 4; ++i) {
        int r = row0 + ty * 4 + i;
        if (r < N) {
            ushort4 o;
            o.x = f2bf(acc[i][0]);
            o.y = f2bf(acc[i][1]);
            o.z = f2bf(acc[i][2]);
            o.w = f2bf(acc[i][3]);
            *(ushort4*)(H + (size_t)r * DMODEL + col0 + tx * 4) = o;
        }
    }
}

// ---------------------------------------------------------------------------
__global__ __launch_bounds__(256) void k_zero(int* __restrict__ p, int n) {
    int i = blockIdx.x * 256 + threadIdx.x;
    if (i < n) p[i] = 0;
}

// ---------------------------------------------------------------------------
// Phase A: bucket histogram (LDS-staged), 1024 threads, int4 loads
// ---------------------------------------------------------------------------
__global__ __launch_bounds__(1024) void k_bhist(const int* __restrict__ er,
                                                int* __restrict__ gcnt_p,
                                                int E, int NBK, int chunk) {
    __shared__ int lh[NBK_MAX];
    const int t = threadIdx.x;
    for (int k = t; k < NBK; k += 1024) lh[k] = 0;
    __syncthreads();
    const int s0 = blockIdx.x * chunk;          // chunk is a multiple of 4
    const int s1 = min(E, s0 + chunk);
    for (int i = s0 + t * 4; i < s1; i += 4096) {
        if (i + 3 < s1) {
            int4 r = *(const int4*)(er + i);
            atomicAdd(&lh[r.x >> 6], 1);
            atomicAdd(&lh[r.y >> 6], 1);
            atomicAdd(&lh[r.z >> 6], 1);
            atomicAdd(&lh[r.w >> 6], 1);
        } else {
            for (int q = i; q < s1; ++q) atomicAdd(&lh[er[q] >> 6], 1);
        }
    }
    __syncthreads();
    for (int k = t; k < NBK; k += 1024) {
        int c = lh[k];
        if (c) atomicAdd(&gcnt_p[k * CPAD], c);
    }
}

// ---------------------------------------------------------------------------
// Phase B: exclusive scan of NBK bucket counts -> bptr[NBK+1], gcur_p
// ---------------------------------------------------------------------------
__global__ __launch_bounds__(256) void k_bscan(const int* __restrict__ gcnt_p,
                                               int* __restrict__ bptr,
                                               int* __restrict__ gcur_p, int NBK) {
    __shared__ int ps[256];
    const int t = threadIdx.x;
    const int SEG = (NBK + 255) >> 8;     // <= 16 for NBK <= 4096
    const int base = t * SEG;
    int cnt[16];
    int s = 0;
    for (int i = 0; i < SEG; ++i) {
        int idx = base + i;
        int c = (idx < NBK) ? gcnt_p[idx * CPAD] : 0;
        cnt[i] = c;
        s += c;
    }
    ps[t] = s;
    __syncthreads();
    for (int o = 1; o < 256; o <<= 1) {
        int x = (t >= o) ? ps[t - o] : 0;
        __syncthreads();
        ps[t] += x;
        __syncthreads();
    }
    int run = (t > 0) ? ps[t - 1] : 0;
    for (int i = 0; i < SEG; ++i) {
        int idx = base + i;
        if (idx < NBK) {
            bptr[idx] = run;
            gcur_p[idx * CPAD] = run;
            run += cnt[i];
        }
    }
    if (t == 255) bptr[NBK] = ps[255];
}

// ---------------------------------------------------------------------------
// Phase C: scatter edges into bucket-grouped array with block-level
// range reservation. 1024 threads, vector loads.
// entry: x = (row_local << 17) | col ; y = f32 edge value
// ---------------------------------------------------------------------------
__global__ __launch_bounds__(1024) void k_bscat(const int* __restrict__ er,
                                                const int* __restrict__ ec,
                                                const float* __restrict__ ev,
                                                int* __restrict__ gcur_p,
                                                int2* __restrict__ packed0,
                                                int E, int NBK, int chunk) {
    __shared__ int lh[NBK_MAX];
    __shared__ int lb[NBK_MAX];
    const int t = threadIdx.x;
    for (int k = t; k < NBK; k += 1024) lh[k] = 0;
    __syncthreads();
    const int s0 = blockIdx.x * chunk;          // multiple of 4
    const int s1 = min(E, s0 + chunk);
    for (int i = s0 + t * 4; i < s1; i += 4096) {
        if (i + 3 < s1) {
            int4 r = *(const int4*)(er + i);
            atomicAdd(&lh[r.x >> 6], 1);
            atomicAdd(&lh[r.y >> 6], 1);
            atomicAdd(&lh[r.z >> 6], 1);
            atomicAdd(&lh[r.w >> 6], 1);
        } else {
            for (int q = i; q < s1; ++q) atomicAdd(&lh[er[q] >> 6], 1);
        }
    }
    __syncthreads();
    for (int k = t; k < NBK; k += 1024) {
        int c = lh[k];
        lb[k] = c ? atomicAdd(&gcur_p[k * CPAD], c) : 0;
        lh[k] = 0;   // reuse as local cursor
    }
    __syncthreads();
    for (int i = s0 + t * 4; i < s1; i += 4096) {
        if (i + 3 < s1) {
            int4 r = *(const int4*)(er + i);
            int4 c = *(const int4*)(ec + i);
            float4 v = *(const float4*)(ev + i);
            int bkt, slot;
            bkt = r.x >> 6; slot = atomicAdd(&lh[bkt], 1);
            packed0[lb[bkt] + slot] = make_int2(((r.x & 63) << 17) | c.x, __float_as_int(v.x));
            bkt = r.y >> 6; slot = atomicAdd(&lh[bkt], 1);
            packed0[lb[bkt] + slot] = make_int2(((r.y & 63) << 17) | c.y, __float_as_int(v.y));
            bkt = r.z >> 6; slot = atomicAdd(&lh[bkt], 1);
            packed0[lb[bkt] + slot] = make_int2(((r.z & 63) << 17) | c.z, __float_as_int(v.z));
            bkt = r.w >> 6; slot = atomicAdd(&lh[bkt], 1);
            packed0[lb[bkt] + slot] = make_int2(((r.w & 63) << 17) | c.w, __float_as_int(v.w));
        } else {
            for (int q = i; q < s1; ++q) {
                int r = er[q];
                int bkt = r >> 6;
                int slot = atomicAdd(&lh[bkt], 1);
                packed0[lb[bkt] + slot] = make_int2(((r & 63) << 17) | ec[q], __float_as_int(ev[q]));
            }
        }
    }
}

// ---------------------------------------------------------------------------
// Phase D: per-bucket regroup -> exact per-node CSR (packed1, row_ptr, row_end).
// ---------------------------------------------------------------------------
__global__ __launch_bounds__(256) void k_regroup(const int2* __restrict__ packed0,
                                                 const int* __restrict__ bptr,
                                                 int2* __restrict__ packed1,
                                                 int* __restrict__ row_ptr,
                                                 int* __restrict__ row_end, int N) {
    __shared__ int lcnt[NPB];
    __shared__ int lpref[NPB];
    __shared__ int lcur[NPB];
    const int t = threadIdx.x;
    const int b = blockIdx.x;
    if (t < NPB) { lcnt[t] = 0; lcur[t] = 0; }
    __syncthreads();
    const int s = bptr[b], e = bptr[b + 1];
    for (int i = s + t; i < e; i += 256)
        atomicAdd(&lcnt[((uint)packed0[i].x) >> 17], 1);
    __syncthreads();
    if (t < NPB) {
        int p = 0;
        for (int k = 0; k < t; ++k) p += lcnt[k];
        lpref[t] = p;
        const int node = b * NPB + t;
        if (node < N) {
            row_ptr[node] = s + p;
            row_end[node] = s + p + lcnt[t];
        }
    }
    __syncthreads();
    for (int i = s + t; i < e; i += 256) {
        int2 en = packed0[i];
        const int rl = ((uint)en.x) >> 17;
        const int pos = s + lpref[rl] + atomicAdd(&lcur[rl], 1);
        packed1[pos] = make_int2(en.x & 0x1FFFF, en.y);
    }
}

// ---------------------------------------------------------------------------
// Aggregate: one wave per dest node; each lane owns 2 bf16 columns of H.
// ---------------------------------------------------------------------------
__global__ __launch_bounds__(256) void k_agg(const uint* __restrict__ Hb,
                                             const int* __restrict__ row_ptr,
                                             const int* __restrict__ row_end,
                                             const int2* __restrict__ packed1,
                                             const float* __restrict__ bias,
                                             float* __restrict__ out, int N) {
    const int wid = threadIdx.x >> 6, lane = threadIdx.x & 63;
    const int n = blockIdx.x * 4 + wid;
    if (n >= N) return;
    const int start = row_ptr[n], end = row_end[n];
    float ax = 0.f, ay = 0.f;
    for (int base = start; base < end; base += 64) {
        const int m = min(64, end - base);
        int2 p = make_int2(0, 0);
        if (lane < m) p = packed1[base + lane];
        int j = 0;
        for (; j + 4 <= m; j += 4) {
#pragma unroll
            for (int q = 0; q < 4; ++q) {
                const int col = __builtin_amdgcn_readlane(p.x, j + q);
                const float v = __int_as_float(__builtin_amdgcn_readlane(p.y, j + q));
                const uint u = Hb[(size_t)col * 64 + lane];
                ax = fmaf(v, __uint_as_float(u << 16), ax);
                ay = fmaf(v, __uint_as_float(u & 0xffff0000u), ay);
            }
        }
        for (; j < m; ++j) {
            const int col = __builtin_amdgcn_readlane(p.x, j);
            const float v = __int_as_float(__builtin_amdgcn_readlane(p.y, j));
            const uint u = Hb[(size_t)col * 64 + lane];
            ax = fmaf(v, __uint_as_float(u << 16), ax);
            ay = fmaf(v, __uint_as_float(u & 0xffff0000u), ay);
        }
    }
    float2 bv = ((const float2*)bias)[lane];
    float ox = ax + bv.x, oy = ay + bv.y;
    ox = ox >= 0.f ? ox : NEG_SLOPE * ox;
    oy = oy >= 0.f ? oy : NEG_SLOPE * oy;
    ((float2*)(out + (size_t)n * DMODEL))[lane] = make_float2(ox, oy);
}

// ---------------------------------------------------------------------------
extern "C" void kernel_launch(void* const* d_in, const int* in_sizes, int n_in,
                              void* d_out, int out_size, void* d_ws, size_t ws_size,
                              hipStream_t stream) {
    const float* X    = (const float*)d_in[0];
    const int*   er   = (const int*)d_in[1];
    const int*   ec   = (const int*)d_in[2];
    const float* ev   = (const float*)d_in[3];
    const float* W    = (const float*)d_in[4];
    const float* bias = (const float*)d_in[5];
    float* out = (float*)d_out;

    const int N = in_sizes[0] / DMODEL;
    const int E = in_sizes[1];
    const int NBK = (N + NPB - 1) / NPB;   // 1563 for N=100000 (<= NBK_MAX)

    // workspace layout (128B-aligned slabs)
    char* ws = (char*)d_ws;
    size_t off = 0;
    auto alloc = [&](size_t bytes) {
        void* p = ws + off;
        off += (bytes + 127) & ~(size_t)127;
        return p;
    };
    ushort_t* H   = (ushort_t*)alloc((size_t)N * DMODEL * sizeof(ushort_t));
    int* gcnt_p   = (int*)alloc((size_t)NBK * CPAD * sizeof(int));
    int* gcur_p   = (int*)alloc((size_t)NBK * CPAD * sizeof(int));
    int* bptr     = (int*)alloc((size_t)(NBK + 1) * sizeof(int));
    int* row_ptr  = (int*)alloc((size_t)N * sizeof(int));
    int* row_end  = (int*)alloc((size_t)N * sizeof(int));
    int2* packed0 = (int2*)alloc((size_t)E * sizeof(int2));
    int2* packed1 = (int2*)alloc((size_t)E * sizeof(int2));
    (void)ws_size;

    // 1) GEMM (f32 in, bf16 out)
    const int gemm_blocks = ((N + 63) / 64) * 2;
    hipLaunchKernelGGL(k_gemm, dim3(gemm_blocks), dim3(256), 0, stream, X, W, H, N);

    // 2) two-level edge grouping (high-TLP: 256 blocks x 1024 threads)
    const int NBLK = 256;
    const int chunk = ((((E + NBLK - 1) / NBLK) + 3) & ~3);   // multiple of 4
    hipLaunchKernelGGL(k_zero,  dim3((NBK * CPAD + 255) / 256), dim3(256), 0, stream,
                       gcnt_p, NBK * CPAD);
    hipLaunchKernelGGL(k_bhist, dim3(NBLK), dim3(1024), 0, stream, er, gcnt_p, E, NBK, chunk);
    hipLaunchKernelGGL(k_bscan, dim3(1), dim3(256), 0, stream, gcnt_p, bptr, gcur_p, NBK);
    hipLaunchKernelGGL(k_bscat, dim3(NBLK), dim3(1024), 0, stream,
                       er, ec, ev, gcur_p, packed0, E, NBK, chunk);
    hipLaunchKernelGGL(k_regroup, dim3(NBK), dim3(256), 0, stream,
                       packed0, bptr, packed1, row_ptr, row_end, N);

    // 3) gather-aggregate, one wave per node
    hipLaunchKernelGGL(k_agg, dim3((N + 3) / 4), dim3(256), 0, stream,
                       (const uint*)H, row_ptr, row_end, packed1, bias, out, N);
}

// Round 6
// 186.047 us; speedup vs baseline: 7.0356x; 1.0755x over previous
//
#include <hip/hip_runtime.h>

#define DMODEL 128
#define NEG_SLOPE 0.01f
#define NPB 64              // nodes per bucket
#define NBK_MAX 1600        // max buckets supported by LDS arrays (N <= 102400)
#define CPAD 16             // counter padding (ints) -> one counter per 64B line

typedef unsigned int uint;
typedef unsigned short ushort_t;
typedef __attribute__((ext_vector_type(8))) short short8v;   // 8 bf16 (4 VGPRs)
typedef __attribute__((ext_vector_type(4))) float float4v;   // MFMA acc

// round-to-nearest-even f32 -> bf16
__device__ inline ushort_t f2bf(float f) {
    uint u = __float_as_uint(f);
    u += 0x7FFFu + ((u >> 16) & 1u);
    return (ushort_t)(u >> 16);
}

// ---------------------------------------------------------------------------
// W transpose + bf16 convert: Wt[c][k] = bf16(W[k][c]);  128x128, one-time.
// ---------------------------------------------------------------------------
__global__ __launch_bounds__(256) void k_wt(const float* __restrict__ W,
                                            ushort_t* __restrict__ Wt) {
    const int t = blockIdx.x * 256 + threadIdx.x;   // 16384 threads
    const int k = t >> 7, c = t & 127;
    Wt[(size_t)c * DMODEL + k] = f2bf(W[(size_t)k * DMODEL + c]);   // coalesced read
}

// ---------------------------------------------------------------------------
// GEMM via MFMA: H(bf16) = bf16(X) @ bf16(W).  One wave per 16 rows, no LDS.
// A-frag: lane reads 8 contiguous f32 of row (lane&15), k=(lane>>4)*8 (+s*32).
// B-frag: 16B load from Wt[col][k] (W^T bf16, L1-hot).
// C/D: col=lane&15, row=(lane>>4)*4+reg (verified gfx950 mapping).
// ---------------------------------------------------------------------------
__global__ __launch_bounds__(256) void k_gemm(const float* __restrict__ X,
                                              const ushort_t* __restrict__ Wt,
                                              ushort_t* __restrict__ H, int N) {
    const int t = threadIdx.x;
    const int wid = t >> 6, lane = t & 63;
    const int wrow = (blockIdx.x * 4 + wid) * 16;    // 16 rows per wave
    if (wrow >= N) return;                           // N % 16 == 0 assumed (100000 ok)
    const int lr = lane & 15;                        // A-row / B-col / C-col in tile
    const int kg = lane >> 4;                        // k-group 0..3

    const float* xrow = X + (size_t)(wrow + lr) * DMODEL + kg * 8;
    const ushort_t* wtb = Wt + (size_t)lr * DMODEL + kg * 8;

    float4v acc[8] = {};                             // 8 col-tiles x 4 f32
#pragma unroll
    for (int s = 0; s < 4; ++s) {                    // k-steps of 32
        float4 x0 = *(const float4*)(xrow + s * 32);
        float4 x1 = *(const float4*)(xrow + s * 32 + 4);
        short8v af;
        af[0] = (short)f2bf(x0.x); af[1] = (short)f2bf(x0.y);
        af[2] = (short)f2bf(x0.z); af[3] = (short)f2bf(x0.w);
        af[4] = (short)f2bf(x1.x); af[5] = (short)f2bf(x1.y);
        af[6] = (short)f2bf(x1.z); af[7] = (short)f2bf(x1.w);
#pragma unroll
        for (int c = 0; c < 8; ++c) {
            short8v bf = *(const short8v*)(wtb + (size_t)c * 16 * DMODEL + s * 32);
            acc[c] = __builtin_amdgcn_mfma_f32_16x16x32_bf16(af, bf, acc[c], 0, 0, 0);
        }
    }

    // epilogue: H[wrow + kg*4 + r][c*16 + lr] = bf16(acc[c][r])
#pragma unroll
    for (int c = 0; c < 8; ++c) {
#pragma unroll
        for (int r = 0; r < 4; ++r) {
            const int row = wrow + kg * 4 + r;
            H[(size_t)row * DMODEL + c * 16 + lr] = f2bf(acc[c][r]);
        }
    }
}

// ---------------------------------------------------------------------------
__global__ __launch_bounds__(256) void k_zero(int* __restrict__ p, int n) {
    int i = blockIdx.x * 256 + threadIdx.x;
    if (i < n) p[i] = 0;
}

// ---------------------------------------------------------------------------
// Phase A: bucket histogram (LDS-staged), 1024 threads, int4 loads
// ---------------------------------------------------------------------------
__global__ __launch_bounds__(1024) void k_bhist(const int* __restrict__ er,
                                                int* __restrict__ gcnt_p,
                                                int E, int NBK, int chunk) {
    __shared__ int lh[NBK_MAX];
    const int t = threadIdx.x;
    for (int k = t; k < NBK; k += 1024) lh[k] = 0;
    __syncthreads();
    const int s0 = blockIdx.x * chunk;          // chunk is a multiple of 4
    const int s1 = min(E, s0 + chunk);
    for (int i = s0 + t * 4; i < s1; i += 4096) {
        if (i + 3 < s1) {
            int4 r = *(const int4*)(er + i);
            atomicAdd(&lh[r.x >> 6], 1);
            atomicAdd(&lh[r.y >> 6], 1);
            atomicAdd(&lh[r.z >> 6], 1);
            atomicAdd(&lh[r.w >> 6], 1);
        } else {
            for (int q = i; q < s1; ++q) atomicAdd(&lh[er[q] >> 6], 1);
        }
    }
    __syncthreads();
    for (int k = t; k < NBK; k += 1024) {
        int c = lh[k];
        if (c) atomicAdd(&gcnt_p[k * CPAD], c);
    }
}

// ---------------------------------------------------------------------------
// Phase B: exclusive scan of NBK bucket counts -> bptr[NBK+1], gcur_p
// ---------------------------------------------------------------------------
__global__ __launch_bounds__(256) void k_bscan(const int* __restrict__ gcnt_p,
                                               int* __restrict__ bptr,
                                               int* __restrict__ gcur_p, int NBK) {
    __shared__ int ps[256];
    const int t = threadIdx.x;
    const int SEG = (NBK + 255) >> 8;     // <= 16 for NBK <= 4096
    const int base = t * SEG;
    int cnt[16];
    int s = 0;
    for (int i = 0; i < SEG; ++i) {
        int idx = base + i;
        int c = (idx < NBK) ? gcnt_p[idx * CPAD] : 0;
        cnt[i] = c;
        s += c;
    }
    ps[t] = s;
    __syncthreads();
    for (int o = 1; o < 256; o <<= 1) {
        int x = (t >= o) ? ps[t - o] : 0;
        __syncthreads();
        ps[t] += x;
        __syncthreads();
    }
    int run = (t > 0) ? ps[t - 1] : 0;
    for (int i = 0; i < SEG; ++i) {
        int idx = base + i;
        if (idx < NBK) {
            bptr[idx] = run;
            gcur_p[idx * CPAD] = run;
            run += cnt[i];
        }
    }
    if (t == 255) bptr[NBK] = ps[255];
}

// ---------------------------------------------------------------------------
// Phase C: scatter edges into bucket-grouped array with block-level
// range reservation. 1024 threads, vector loads.
// entry: x = (row_local << 17) | col ; y = f32 edge value
// ---------------------------------------------------------------------------
__global__ __launch_bounds__(1024) void k_bscat(const int* __restrict__ er,
                                                const int* __restrict__ ec,
                                                const float* __restrict__ ev,
                                                int* __restrict__ gcur_p,
                                                int2* __restrict__ packed0,
                                                int E, int NBK, int chunk) {
    __shared__ int lh[NBK_MAX];
    __shared__ int lb[NBK_MAX];
    const int t = threadIdx.x;
    for (int k = t; k < NBK; k += 1024) lh[k] = 0;
    __syncthreads();
    const int s0 = blockIdx.x * chunk;          // multiple of 4
    const int s1 = min(E, s0 + chunk);
    for (int i = s0 + t * 4; i < s1; i += 4096) {
        if (i + 3 < s1) {
            int4 r = *(const int4*)(er + i);
            atomicAdd(&lh[r.x >> 6], 1);
            atomicAdd(&lh[r.y >> 6], 1);
            atomicAdd(&lh[r.z >> 6], 1);
            atomicAdd(&lh[r.w >> 6], 1);
        } else {
            for (int q = i; q < s1; ++q) atomicAdd(&lh[er[q] >> 6], 1);
        }
    }
    __syncthreads();
    for (int k = t; k < NBK; k += 1024) {
        int c = lh[k];
        lb[k] = c ? atomicAdd(&gcur_p[k * CPAD], c) : 0;
        lh[k] = 0;   // reuse as local cursor
    }
    __syncthreads();
    for (int i = s0 + t * 4; i < s1; i += 4096) {
        if (i + 3 < s1) {
            int4 r = *(const int4*)(er + i);
            int4 c = *(const int4*)(ec + i);
            float4 v = *(const float4*)(ev + i);
            int bkt, slot;
            bkt = r.x >> 6; slot = atomicAdd(&lh[bkt], 1);
            packed0[lb[bkt] + slot] = make_int2(((r.x & 63) << 17) | c.x, __float_as_int(v.x));
            bkt = r.y >> 6; slot = atomicAdd(&lh[bkt], 1);
            packed0[lb[bkt] + slot] = make_int2(((r.y & 63) << 17) | c.y, __float_as_int(v.y));
            bkt = r.z >> 6; slot = atomicAdd(&lh[bkt], 1);
            packed0[lb[bkt] + slot] = make_int2(((r.z & 63) << 17) | c.z, __float_as_int(v.z));
            bkt = r.w >> 6; slot = atomicAdd(&lh[bkt], 1);
            packed0[lb[bkt] + slot] = make_int2(((r.w & 63) << 17) | c.w, __float_as_int(v.w));
        } else {
            for (int q = i; q < s1; ++q) {
                int r = er[q];
                int bkt = r >> 6;
                int slot = atomicAdd(&lh[bkt], 1);
                packed0[lb[bkt] + slot] = make_int2(((r & 63) << 17) | ec[q], __float_as_int(ev[q]));
            }
        }
    }
}

// ---------------------------------------------------------------------------
// Phase D: per-bucket regroup -> exact per-node CSR (packed1, row_ptr, row_end).
// ---------------------------------------------------------------------------
__global__ __launch_bounds__(256) void k_regroup(const int2* __restrict__ packed0,
                                                 const int* __restrict__ bptr,
                                                 int2* __restrict__ packed1,
                                                 int* __restrict__ row_ptr,
                                                 int* __restrict__ row_end, int N) {
    __shared__ int lcnt[NPB];
    __shared__ int lpref[NPB];
    __shared__ int lcur[NPB];
    const int t = threadIdx.x;
    const int b = blockIdx.x;
    if (t < NPB) { lcnt[t] = 0; lcur[t] = 0; }
    __syncthreads();
    const int s = bptr[b], e = bptr[b + 1];
    for (int i = s + t; i < e; i += 256)
        atomicAdd(&lcnt[((uint)packed0[i].x) >> 17], 1);
    __syncthreads();
    if (t < NPB) {
        int p = 0;
        for (int k = 0; k < t; ++k) p += lcnt[k];
        lpref[t] = p;
        const int node = b * NPB + t;
        if (node < N) {
            row_ptr[node] = s + p;
            row_end[node] = s + p + lcnt[t];
        }
    }
    __syncthreads();
    for (int i = s + t; i < e; i += 256) {
        int2 en = packed0[i];
        const int rl = ((uint)en.x) >> 17;
        const int pos = s + lpref[rl] + atomicAdd(&lcur[rl], 1);
        packed1[pos] = make_int2(en.x & 0x1FFFF, en.y);
    }
}

// ---------------------------------------------------------------------------
// Aggregate: one wave per dest node; each lane owns 2 bf16 columns of H.
// ---------------------------------------------------------------------------
__global__ __launch_bounds__(256) void k_agg(const uint* __restrict__ Hb,
                                             const int* __restrict__ row_ptr,
                                             const int* __restrict__ row_end,
                                             const int2* __restrict__ packed1,
                                             const float* __restrict__ bias,
                                             float* __restrict__ out, int N) {
    const int wid = threadIdx.x >> 6, lane = threadIdx.x & 63;
    const int n = blockIdx.x * 4 + wid;
    if (n >= N) return;
    const int start = row_ptr[n], end = row_end[n];
    float ax = 0.f, ay = 0.f;
    for (int base = start; base < end; base += 64) {
        const int m = min(64, end - base);
        int2 p = make_int2(0, 0);
        if (lane < m) p = packed1[base + lane];
        int j = 0;
        for (; j + 4 <= m; j += 4) {
#pragma unroll
            for (int q = 0; q < 4; ++q) {
                const int col = __builtin_amdgcn_readlane(p.x, j + q);
                const float v = __int_as_float(__builtin_amdgcn_readlane(p.y, j + q));
                const uint u = Hb[(size_t)col * 64 + lane];
                ax = fmaf(v, __uint_as_float(u << 16), ax);
                ay = fmaf(v, __uint_as_float(u & 0xffff0000u), ay);
            }
        }
        for (; j < m; ++j) {
            const int col = __builtin_amdgcn_readlane(p.x, j);
            const float v = __int_as_float(__builtin_amdgcn_readlane(p.y, j));
            const uint u = Hb[(size_t)col * 64 + lane];
            ax = fmaf(v, __uint_as_float(u << 16), ax);
            ay = fmaf(v, __uint_as_float(u & 0xffff0000u), ay);
        }
    }
    float2 bv = ((const float2*)bias)[lane];
    float ox = ax + bv.x, oy = ay + bv.y;
    ox = ox >= 0.f ? ox : NEG_SLOPE * ox;
    oy = oy >= 0.f ? oy : NEG_SLOPE * oy;
    ((float2*)(out + (size_t)n * DMODEL))[lane] = make_float2(ox, oy);
}

// ---------------------------------------------------------------------------
extern "C" void kernel_launch(void* const* d_in, const int* in_sizes, int n_in,
                              void* d_out, int out_size, void* d_ws, size_t ws_size,
                              hipStream_t stream) {
    const float* X    = (const float*)d_in[0];
    const int*   er   = (const int*)d_in[1];
    const int*   ec   = (const int*)d_in[2];
    const float* ev   = (const float*)d_in[3];
    const float* W    = (const float*)d_in[4];
    const float* bias = (const float*)d_in[5];
    float* out = (float*)d_out;

    const int N = in_sizes[0] / DMODEL;
    const int E = in_sizes[1];
    const int NBK = (N + NPB - 1) / NPB;   // 1563 for N=100000 (<= NBK_MAX)

    // workspace layout (128B-aligned slabs)
    char* ws = (char*)d_ws;
    size_t off = 0;
    auto alloc = [&](size_t bytes) {
        void* p = ws + off;
        off += (bytes + 127) & ~(size_t)127;
        return p;
    };
    ushort_t* H   = (ushort_t*)alloc((size_t)N * DMODEL * sizeof(ushort_t));
    ushort_t* Wt  = (ushort_t*)alloc((size_t)DMODEL * DMODEL * sizeof(ushort_t));
    int* gcnt_p   = (int*)alloc((size_t)NBK * CPAD * sizeof(int));
    int* gcur_p   = (int*)alloc((size_t)NBK * CPAD * sizeof(int));
    int* bptr     = (int*)alloc((size_t)(NBK + 1) * sizeof(int));
    int* row_ptr  = (int*)alloc((size_t)N * sizeof(int));
    int* row_end  = (int*)alloc((size_t)N * sizeof(int));
    int2* packed0 = (int2*)alloc((size_t)E * sizeof(int2));
    int2* packed1 = (int2*)alloc((size_t)E * sizeof(int2));
    (void)ws_size;

    // 1) W^T bf16, then MFMA GEMM (f32 in, bf16 out)
    hipLaunchKernelGGL(k_wt, dim3(64), dim3(256), 0, stream, W, Wt);
    const int gemm_blocks = (N + 63) / 64;           // 4 waves x 16 rows per block
    hipLaunchKernelGGL(k_gemm, dim3(gemm_blocks), dim3(256), 0, stream, X, Wt, H, N);

    // 2) two-level edge grouping (high-TLP: 256 blocks x 1024 threads)
    const int NBLK = 256;
    const int chunk = ((((E + NBLK - 1) / NBLK) + 3) & ~3);   // multiple of 4
    hipLaunchKernelGGL(k_zero,  dim3((NBK * CPAD + 255) / 256), dim3(256), 0, stream,
                       gcnt_p, NBK * CPAD);
    hipLaunchKernelGGL(k_bhist, dim3(NBLK), dim3(1024), 0, stream, er, gcnt_p, E, NBK, chunk);
    hipLaunchKernelGGL(k_bscan, dim3(1), dim3(256), 0, stream, gcnt_p, bptr, gcur_p, NBK);
    hipLaunchKernelGGL(k_bscat, dim3(NBLK), dim3(1024), 0, stream,
                       er, ec, ev, gcur_p, packed0, E, NBK, chunk);
    hipLaunchKernelGGL(k_regroup, dim3(NBK), dim3(256), 0, stream,
                       packed0, bptr, packed1, row_ptr, row_end, N);

    // 3) gather-aggregate, one wave per node
    hipLaunchKernelGGL(k_agg, dim3((N + 3) / 4), dim3(256), 0, stream,
                       (const uint*)H, row_ptr, row_end, packed1, bias, out, N);
}

// Round 7
// 174.987 us; speedup vs baseline: 7.4803x; 1.0632x over previous
//
#include <hip/hip_runtime.h>

#define DMODEL 128
#define NEG_SLOPE 0.01f
#define NPB 64              // nodes per bucket
#define NBK_MAX 1600        // max buckets supported by LDS arrays (N <= 102400)
#define CPAD 16             // counter padding (ints) -> one counter per 64B line
#define NBLK 256            // chunk blocks for hist/scatter (fixed; k_boff assumes 256)

typedef unsigned int uint;
typedef unsigned short ushort_t;
typedef __attribute__((ext_vector_type(8))) short short8v;   // 8 bf16 (4 VGPRs)
typedef __attribute__((ext_vector_type(4))) float float4v;   // MFMA acc

// round-to-nearest-even f32 -> bf16
__device__ inline ushort_t f2bf(float f) {
    uint u = __float_as_uint(f);
    u += 0x7FFFu + ((u >> 16) & 1u);
    return (ushort_t)(u >> 16);
}

// ---------------------------------------------------------------------------
// W transpose + bf16 convert: Wt[c][k] = bf16(W[k][c]);  128x128, one-time.
// ---------------------------------------------------------------------------
__global__ __launch_bounds__(256) void k_wt(const float* __restrict__ W,
                                            ushort_t* __restrict__ Wt) {
    const int t = blockIdx.x * 256 + threadIdx.x;   // 16384 threads
    const int k = t >> 7, c = t & 127;
    Wt[(size_t)c * DMODEL + k] = f2bf(W[(size_t)k * DMODEL + c]);   // coalesced read
}

// ---------------------------------------------------------------------------
// GEMM via MFMA: H(bf16) = bf16(X) @ bf16(W).  One wave per 16 rows, no LDS.
// ---------------------------------------------------------------------------
__global__ __launch_bounds__(256) void k_gemm(const float* __restrict__ X,
                                              const ushort_t* __restrict__ Wt,
                                              ushort_t* __restrict__ H, int N) {
    const int t = threadIdx.x;
    const int wid = t >> 6, lane = t & 63;
    const int wrow = (blockIdx.x * 4 + wid) * 16;    // 16 rows per wave
    if (wrow >= N) return;
    const int lr = lane & 15;                        // A-row / B-col / C-col in tile
    const int kg = lane >> 4;                        // k-group 0..3

    const float* xrow = X + (size_t)(wrow + lr) * DMODEL + kg * 8;
    const ushort_t* wtb = Wt + (size_t)lr * DMODEL + kg * 8;

    float4v acc[8] = {};                             // 8 col-tiles x 4 f32
#pragma unroll
    for (int s = 0; s < 4; ++s) {                    // k-steps of 32
        float4 x0 = *(const float4*)(xrow + s * 32);
        float4 x1 = *(const float4*)(xrow + s * 32 + 4);
        short8v af;
        af[0] = (short)f2bf(x0.x); af[1] = (short)f2bf(x0.y);
        af[2] = (short)f2bf(x0.z); af[3] = (short)f2bf(x0.w);
        af[4] = (short)f2bf(x1.x); af[5] = (short)f2bf(x1.y);
        af[6] = (short)f2bf(x1.z); af[7] = (short)f2bf(x1.w);
#pragma unroll
        for (int c = 0; c < 8; ++c) {
            short8v bf = *(const short8v*)(wtb + (size_t)c * 16 * DMODEL + s * 32);
            acc[c] = __builtin_amdgcn_mfma_f32_16x16x32_bf16(af, bf, acc[c], 0, 0, 0);
        }
    }
#pragma unroll
    for (int c = 0; c < 8; ++c) {
#pragma unroll
        for (int r = 0; r < 4; ++r) {
            const int row = wrow + kg * 4 + r;
            H[(size_t)row * DMODEL + c * 16 + lr] = f2bf(acc[c][r]);
        }
    }
}

// ---------------------------------------------------------------------------
__global__ __launch_bounds__(256) void k_zero(int* __restrict__ p, int n) {
    int i = blockIdx.x * 256 + threadIdx.x;
    if (i < n) p[i] = 0;
}

// ---------------------------------------------------------------------------
// Phase A: bucket histogram; stores per-block counts (bcnt) + global totals.
// ---------------------------------------------------------------------------
__global__ __launch_bounds__(1024) void k_bhist(const int* __restrict__ er,
                                                int* __restrict__ gcnt_p,
                                                int* __restrict__ bcnt,
                                                int E, int NBK, int chunk) {
    __shared__ int lh[NBK_MAX];
    const int t = threadIdx.x;
    for (int k = t; k < NBK; k += 1024) lh[k] = 0;
    __syncthreads();
    const int s0 = blockIdx.x * chunk;          // chunk is a multiple of 4
    const int s1 = min(E, s0 + chunk);
    for (int i = s0 + t * 4; i < s1; i += 4096) {
        if (i + 3 < s1) {
            int4 r = *(const int4*)(er + i);
            atomicAdd(&lh[r.x >> 6], 1);
            atomicAdd(&lh[r.y >> 6], 1);
            atomicAdd(&lh[r.z >> 6], 1);
            atomicAdd(&lh[r.w >> 6], 1);
        } else {
            for (int q = i; q < s1; ++q) atomicAdd(&lh[er[q] >> 6], 1);
        }
    }
    __syncthreads();
    int* brow = bcnt + (size_t)blockIdx.x * NBK;
    for (int k = t; k < NBK; k += 1024) {
        int c = lh[k];
        brow[k] = c;                             // coalesced
        if (c) atomicAdd(&gcnt_p[k * CPAD], c);
    }
}

// ---------------------------------------------------------------------------
// Phase B: exclusive scan of NBK bucket counts -> bptr[NBK+1]
// ---------------------------------------------------------------------------
__global__ __launch_bounds__(256) void k_bscan(const int* __restrict__ gcnt_p,
                                               int* __restrict__ bptr, int NBK) {
    __shared__ int ps[256];
    const int t = threadIdx.x;
    const int SEG = (NBK + 255) >> 8;     // <= 16 for NBK <= 4096
    const int base = t * SEG;
    int cnt[16];
    int s = 0;
    for (int i = 0; i < SEG; ++i) {
        int idx = base + i;
        int c = (idx < NBK) ? gcnt_p[idx * CPAD] : 0;
        cnt[i] = c;
        s += c;
    }
    ps[t] = s;
    __syncthreads();
    for (int o = 1; o < 256; o <<= 1) {
        int x = (t >= o) ? ps[t - o] : 0;
        __syncthreads();
        ps[t] += x;
        __syncthreads();
    }
    int run = (t > 0) ? ps[t - 1] : 0;
    for (int i = 0; i < SEG; ++i) {
        int idx = base + i;
        if (idx < NBK) {
            bptr[idx] = run;
            run += cnt[i];
        }
    }
    if (t == 255) bptr[NBK] = ps[255];
}

// ---------------------------------------------------------------------------
// Phase B2: per-(chunk-block, bucket) offsets. One wave per bucket; ordered
// prefix over the 256 chunk blocks. boff[block][bucket] = start position.
// ---------------------------------------------------------------------------
__global__ __launch_bounds__(64) void k_boff(const int* __restrict__ bcnt,
                                             const int* __restrict__ bptr,
                                             int* __restrict__ boff, int NBK) {
    const int b = blockIdx.x;           // bucket
    const int l = threadIdx.x;          // lane, owns chunk blocks 4l..4l+3
    int c0 = bcnt[(size_t)(4 * l + 0) * NBK + b];
    int c1 = bcnt[(size_t)(4 * l + 1) * NBK + b];
    int c2 = bcnt[(size_t)(4 * l + 2) * NBK + b];
    int c3 = bcnt[(size_t)(4 * l + 3) * NBK + b];
    int s = c0 + c1 + c2 + c3;
    int ps = s;
    for (int o = 1; o < 64; o <<= 1) {
        int x = __shfl_up(ps, o);
        if (l >= o) ps += x;
    }
    int base = bptr[b] + (ps - s);      // exclusive prefix
    boff[(size_t)(4 * l + 0) * NBK + b] = base;
    boff[(size_t)(4 * l + 1) * NBK + b] = base + c0;
    boff[(size_t)(4 * l + 2) * NBK + b] = base + c0 + c1;
    boff[(size_t)(4 * l + 3) * NBK + b] = base + c0 + c1 + c2;
}

// ---------------------------------------------------------------------------
// Phase C: single-pass scatter. LDS cursors preloaded from boff (exact,
// disjoint ranges per block). entry: x = (row_local << 17) | col ; y = value
// ---------------------------------------------------------------------------
__global__ __launch_bounds__(1024) void k_bscat(const int* __restrict__ er,
                                                const int* __restrict__ ec,
                                                const float* __restrict__ ev,
                                                const int* __restrict__ boff,
                                                int2* __restrict__ packed0,
                                                int E, int NBK, int chunk) {
    __shared__ int lh[NBK_MAX];
    const int t = threadIdx.x;
    const int* brow = boff + (size_t)blockIdx.x * NBK;
    for (int k = t; k < NBK; k += 1024) lh[k] = brow[k];   // coalesced
    __syncthreads();
    const int s0 = blockIdx.x * chunk;          // multiple of 4
    const int s1 = min(E, s0 + chunk);
    for (int i = s0 + t * 4; i < s1; i += 4096) {
        if (i + 3 < s1) {
            int4 r = *(const int4*)(er + i);
            int4 c = *(const int4*)(ec + i);
            float4 v = *(const float4*)(ev + i);
            int bkt, slot;
            bkt = r.x >> 6; slot = atomicAdd(&lh[bkt], 1);
            packed0[slot] = make_int2(((r.x & 63) << 17) | c.x, __float_as_int(v.x));
            bkt = r.y >> 6; slot = atomicAdd(&lh[bkt], 1);
            packed0[slot] = make_int2(((r.y & 63) << 17) | c.y, __float_as_int(v.y));
            bkt = r.z >> 6; slot = atomicAdd(&lh[bkt], 1);
            packed0[slot] = make_int2(((r.z & 63) << 17) | c.z, __float_as_int(v.z));
            bkt = r.w >> 6; slot = atomicAdd(&lh[bkt], 1);
            packed0[slot] = make_int2(((r.w & 63) << 17) | c.w, __float_as_int(v.w));
        } else {
            for (int q = i; q < s1; ++q) {
                int r = er[q];
                int bkt = r >> 6;
                int slot = atomicAdd(&lh[bkt], 1);
                packed0[slot] = make_int2(((r & 63) << 17) | ec[q], __float_as_int(ev[q]));
            }
        }
    }
}

// ---------------------------------------------------------------------------
// Phase D: per-bucket regroup -> exact per-node CSR (packed1, row_ptr, row_end).
// ---------------------------------------------------------------------------
__global__ __launch_bounds__(256) void k_regroup(const int2* __restrict__ packed0,
                                                 const int* __restrict__ bptr,
                                                 int2* __restrict__ packed1,
                                                 int* __restrict__ row_ptr,
                                                 int* __restrict__ row_end, int N) {
    __shared__ int lcnt[NPB];
    __shared__ int lpref[NPB];
    __shared__ int lcur[NPB];
    const int t = threadIdx.x;
    const int b = blockIdx.x;
    if (t < NPB) { lcnt[t] = 0; lcur[t] = 0; }
    __syncthreads();
    const int s = bptr[b], e = bptr[b + 1];
    for (int i = s + t; i < e; i += 256)
        atomicAdd(&lcnt[((uint)packed0[i].x) >> 17], 1);
    __syncthreads();
    if (t < NPB) {
        int p = 0;
        for (int k = 0; k < t; ++k) p += lcnt[k];
        lpref[t] = p;
        const int node = b * NPB + t;
        if (node < N) {
            row_ptr[node] = s + p;
            row_end[node] = s + p + lcnt[t];
        }
    }
    __syncthreads();
    for (int i = s + t; i < e; i += 256) {
        int2 en = packed0[i];
        const int rl = ((uint)en.x) >> 17;
        const int pos = s + lpref[rl] + atomicAdd(&lcur[rl], 1);
        packed1[pos] = make_int2(en.x & 0x1FFFF, en.y);
    }
}

// ---------------------------------------------------------------------------
// Aggregate v2: one wave per dest node, split into two 32-lane halves.
// Half h processes edges 2j+h (same node -> no imbalance). Each lane gathers
// uint2 (4 bf16 feats); metadata broadcast via ds_bpermute from the 64-entry
// lane prefetch. Cross-half combine via shfl_xor(32) at the end.
// ---------------------------------------------------------------------------
__global__ __launch_bounds__(256) void k_agg(const uint* __restrict__ Hb,
                                             const int* __restrict__ row_ptr,
                                             const int* __restrict__ row_end,
                                             const int2* __restrict__ packed1,
                                             const float* __restrict__ bias,
                                             float* __restrict__ out, int N) {
    const int wid = threadIdx.x >> 6, lane = threadIdx.x & 63;
    const int n = blockIdx.x * 4 + wid;
    if (n >= N) return;
    const int h = lane >> 5, sl = lane & 31;
    const int start = row_ptr[n], end = row_end[n];
    float4 acc = make_float4(0.f, 0.f, 0.f, 0.f);
    for (int base = start; base < end; base += 64) {
        const int m = min(64, end - base);
        int2 p = make_int2(0, 0);
        if (lane < m) p = packed1[base + lane];
        const int npair = (m + 1) >> 1;
        for (int j = 0; j < npair; j += 2) {
            const int e0 = 2 * j + h;
            const int e1 = e0 + 2;
            int c0 = __builtin_amdgcn_ds_bpermute(e0 << 2, p.x);
            int w0 = __builtin_amdgcn_ds_bpermute(e0 << 2, p.y);
            int c1 = __builtin_amdgcn_ds_bpermute((e1 & 63) << 2, p.x);
            int w1 = __builtin_amdgcn_ds_bpermute((e1 & 63) << 2, p.y);
            const bool q0 = e0 < m;
            const bool q1 = (j + 1 < npair) && (e1 < m);
            c0 = q0 ? c0 : 0;
            c1 = q1 ? c1 : 0;
            const float v0 = q0 ? __int_as_float(w0) : 0.f;
            const float v1 = q1 ? __int_as_float(w1) : 0.f;
            const uint2 g0 = ((const uint2*)(Hb + (size_t)c0 * 64))[sl];
            const uint2 g1 = ((const uint2*)(Hb + (size_t)c1 * 64))[sl];
            acc.x = fmaf(v0, __uint_as_float(g0.x << 16), acc.x);
            acc.y = fmaf(v0, __uint_as_float(g0.x & 0xffff0000u), acc.y);
            acc.z = fmaf(v0, __uint_as_float(g0.y << 16), acc.z);
            acc.w = fmaf(v0, __uint_as_float(g0.y & 0xffff0000u), acc.w);
            acc.x = fmaf(v1, __uint_as_float(g1.x << 16), acc.x);
            acc.y = fmaf(v1, __uint_as_float(g1.x & 0xffff0000u), acc.y);
            acc.z = fmaf(v1, __uint_as_float(g1.y << 16), acc.z);
            acc.w = fmaf(v1, __uint_as_float(g1.y & 0xffff0000u), acc.w);
        }
    }
    acc.x += __shfl_xor(acc.x, 32);
    acc.y += __shfl_xor(acc.y, 32);
    acc.z += __shfl_xor(acc.z, 32);
    acc.w += __shfl_xor(acc.w, 32);
    const float4 bv = ((const float4*)bias)[sl];
    float4 o;
    o.x = acc.x + bv.x; o.y = acc.y + bv.y;
    o.z = acc.z + bv.z; o.w = acc.w + bv.w;
    o.x = o.x >= 0.f ? o.x : NEG_SLOPE * o.x;
    o.y = o.y >= 0.f ? o.y : NEG_SLOPE * o.y;
    o.z = o.z >= 0.f ? o.z : NEG_SLOPE * o.z;
    o.w = o.w >= 0.f ? o.w : NEG_SLOPE * o.w;
    if (h == 0) ((float4*)(out + (size_t)n * DMODEL))[sl] = o;
}

// ---------------------------------------------------------------------------
extern "C" void kernel_launch(void* const* d_in, const int* in_sizes, int n_in,
                              void* d_out, int out_size, void* d_ws, size_t ws_size,
                              hipStream_t stream) {
    const float* X    = (const float*)d_in[0];
    const int*   er   = (const int*)d_in[1];
    const int*   ec   = (const int*)d_in[2];
    const float* ev   = (const float*)d_in[3];
    const float* W    = (const float*)d_in[4];
    const float* bias = (const float*)d_in[5];
    float* out = (float*)d_out;

    const int N = in_sizes[0] / DMODEL;
    const int E = in_sizes[1];
    const int NBK = (N + NPB - 1) / NPB;   // 1563 for N=100000 (<= NBK_MAX)

    // workspace layout (128B-aligned slabs)
    char* ws = (char*)d_ws;
    size_t off = 0;
    auto alloc = [&](size_t bytes) {
        void* p = ws + off;
        off += (bytes + 127) & ~(size_t)127;
        return p;
    };
    ushort_t* H   = (ushort_t*)alloc((size_t)N * DMODEL * sizeof(ushort_t));
    ushort_t* Wt  = (ushort_t*)alloc((size_t)DMODEL * DMODEL * sizeof(ushort_t));
    int* gcnt_p   = (int*)alloc((size_t)NBK * CPAD * sizeof(int));
    int* bptr     = (int*)alloc((size_t)(NBK + 1) * sizeof(int));
    int* bcnt     = (int*)alloc((size_t)NBLK * NBK * sizeof(int));
    int* boff     = (int*)alloc((size_t)NBLK * NBK * sizeof(int));
    int* row_ptr  = (int*)alloc((size_t)N * sizeof(int));
    int* row_end  = (int*)alloc((size_t)N * sizeof(int));
    int2* packed0 = (int2*)alloc((size_t)E * sizeof(int2));
    int2* packed1 = (int2*)alloc((size_t)(E + 4) * sizeof(int2));
    (void)ws_size;

    // 1) W^T bf16, then MFMA GEMM (f32 in, bf16 out)
    hipLaunchKernelGGL(k_wt, dim3(64), dim3(256), 0, stream, W, Wt);
    const int gemm_blocks = (N + 63) / 64;           // 4 waves x 16 rows per block
    hipLaunchKernelGGL(k_gemm, dim3(gemm_blocks), dim3(256), 0, stream, X, Wt, H, N);

    // 2) two-level edge grouping (single-pass scatter via stored counts)
    const int chunk = ((((E + NBLK - 1) / NBLK) + 3) & ~3);   // multiple of 4
    hipLaunchKernelGGL(k_zero,  dim3((NBK * CPAD + 255) / 256), dim3(256), 0, stream,
                       gcnt_p, NBK * CPAD);
    hipLaunchKernelGGL(k_bhist, dim3(NBLK), dim3(1024), 0, stream,
                       er, gcnt_p, bcnt, E, NBK, chunk);
    hipLaunchKernelGGL(k_bscan, dim3(1), dim3(256), 0, stream, gcnt_p, bptr, NBK);
    hipLaunchKernelGGL(k_boff,  dim3(NBK), dim3(64), 0, stream, bcnt, bptr, boff, NBK);
    hipLaunchKernelGGL(k_bscat, dim3(NBLK), dim3(1024), 0, stream,
                       er, ec, ev, boff, packed0, E, NBK, chunk);
    hipLaunchKernelGGL(k_regroup, dim3(NBK), dim3(256), 0, stream,
                       packed0, bptr, packed1, row_ptr, row_end, N);

    // 3) gather-aggregate, one wave per node (half-wave edge pairs)
    hipLaunchKernelGGL(k_agg, dim3((N + 3) / 4), dim3(256), 0, stream,
                       (const uint*)H, row_ptr, row_end, packed1, bias, out, N);
}

// Round 8
// 163.209 us; speedup vs baseline: 8.0201x; 1.0722x over previous
//
#include <hip/hip_runtime.h>

#define DMODEL 128
#define NEG_SLOPE 0.01f
#define NPB 64              // nodes per bucket
#define NBK_MAX 1600        // max buckets supported by LDS arrays (N <= 102400)
#define CPAD 16             // counter padding (ints) -> one counter per 64B line
#define NBLK 256            // chunk blocks for hist/scatter (k_boff assumes 256)
#define SCAP 2048           // staged entries per bucket in k_bagg2

typedef unsigned int uint;
typedef unsigned short ushort_t;
typedef __attribute__((ext_vector_type(8))) short short8v;   // 8 bf16 (4 VGPRs)
typedef __attribute__((ext_vector_type(4))) float float4v;   // MFMA acc

// round-to-nearest-even f32 -> bf16
__device__ inline ushort_t f2bf(float f) {
    uint u = __float_as_uint(f);
    u += 0x7FFFu + ((u >> 16) & 1u);
    return (ushort_t)(u >> 16);
}

// ---------------------------------------------------------------------------
// Setup: blocks 0..63 build Wt[c][k] = bf16(W[k][c]); the rest zero gcnt_p.
// ---------------------------------------------------------------------------
__global__ __launch_bounds__(256) void k_setup(const float* __restrict__ W,
                                               ushort_t* __restrict__ Wt,
                                               int* __restrict__ gcnt_p, int ztot) {
    const int b = blockIdx.x;
    if (b < 64) {
        const int t = b * 256 + threadIdx.x;          // 16384 threads
        const int k = t >> 7, c = t & 127;
        Wt[(size_t)c * DMODEL + k] = f2bf(W[(size_t)k * DMODEL + c]);
    } else {
        const int i = (b - 64) * 256 + threadIdx.x;
        if (i < ztot) gcnt_p[i] = 0;
    }
}

// ---------------------------------------------------------------------------
// GEMM via MFMA: H(bf16) = bf16(X) @ bf16(W).  One wave per 16 rows, no LDS.
// ---------------------------------------------------------------------------
__global__ __launch_bounds__(256) void k_gemm(const float* __restrict__ X,
                                              const ushort_t* __restrict__ Wt,
                                              ushort_t* __restrict__ H, int N) {
    const int t = threadIdx.x;
    const int wid = t >> 6, lane = t & 63;
    const int wrow = (blockIdx.x * 4 + wid) * 16;    // 16 rows per wave
    if (wrow >= N) return;
    const int lr = lane & 15;                        // A-row / B-col / C-col in tile
    const int kg = lane >> 4;                        // k-group 0..3

    const float* xrow = X + (size_t)(wrow + lr) * DMODEL + kg * 8;
    const ushort_t* wtb = Wt + (size_t)lr * DMODEL + kg * 8;

    float4v acc[8] = {};                             // 8 col-tiles x 4 f32
#pragma unroll
    for (int s = 0; s < 4; ++s) {                    // k-steps of 32
        float4 x0 = *(const float4*)(xrow + s * 32);
        float4 x1 = *(const float4*)(xrow + s * 32 + 4);
        short8v af;
        af[0] = (short)f2bf(x0.x); af[1] = (short)f2bf(x0.y);
        af[2] = (short)f2bf(x0.z); af[3] = (short)f2bf(x0.w);
        af[4] = (short)f2bf(x1.x); af[5] = (short)f2bf(x1.y);
        af[6] = (short)f2bf(x1.z); af[7] = (short)f2bf(x1.w);
#pragma unroll
        for (int c = 0; c < 8; ++c) {
            short8v bf = *(const short8v*)(wtb + (size_t)c * 16 * DMODEL + s * 32);
            acc[c] = __builtin_amdgcn_mfma_f32_16x16x32_bf16(af, bf, acc[c], 0, 0, 0);
        }
    }
#pragma unroll
    for (int c = 0; c < 8; ++c) {
#pragma unroll
        for (int r = 0; r < 4; ++r) {
            const int row = wrow + kg * 4 + r;
            H[(size_t)row * DMODEL + c * 16 + lr] = f2bf(acc[c][r]);
        }
    }
}

// ---------------------------------------------------------------------------
// Phase A: bucket histogram; stores per-block counts (bcnt) + global totals.
// ---------------------------------------------------------------------------
__global__ __launch_bounds__(1024) void k_bhist(const int* __restrict__ er,
                                                int* __restrict__ gcnt_p,
                                                int* __restrict__ bcnt,
                                                int E, int NBK, int chunk) {
    __shared__ int lh[NBK_MAX];
    const int t = threadIdx.x;
    for (int k = t; k < NBK; k += 1024) lh[k] = 0;
    __syncthreads();
    const int s0 = blockIdx.x * chunk;          // chunk is a multiple of 4
    const int s1 = min(E, s0 + chunk);
    for (int i = s0 + t * 4; i < s1; i += 4096) {
        if (i + 3 < s1) {
            int4 r = *(const int4*)(er + i);
            atomicAdd(&lh[r.x >> 6], 1);
            atomicAdd(&lh[r.y >> 6], 1);
            atomicAdd(&lh[r.z >> 6], 1);
            atomicAdd(&lh[r.w >> 6], 1);
        } else {
            for (int q = i; q < s1; ++q) atomicAdd(&lh[er[q] >> 6], 1);
        }
    }
    __syncthreads();
    int* brow = bcnt + (size_t)blockIdx.x * NBK;
    for (int k = t; k < NBK; k += 1024) {
        int c = lh[k];
        brow[k] = c;                             // coalesced
        if (c) atomicAdd(&gcnt_p[k * CPAD], c);
    }
}

// ---------------------------------------------------------------------------
// Phase B: exclusive scan of NBK bucket counts -> bptr[NBK+1]
// ---------------------------------------------------------------------------
__global__ __launch_bounds__(256) void k_bscan(const int* __restrict__ gcnt_p,
                                               int* __restrict__ bptr, int NBK) {
    __shared__ int ps[256];
    const int t = threadIdx.x;
    const int SEG = (NBK + 255) >> 8;     // <= 16 for NBK <= 4096
    const int base = t * SEG;
    int cnt[16];
    int s = 0;
    for (int i = 0; i < SEG; ++i) {
        int idx = base + i;
        int c = (idx < NBK) ? gcnt_p[idx * CPAD] : 0;
        cnt[i] = c;
        s += c;
    }
    ps[t] = s;
    __syncthreads();
    for (int o = 1; o < 256; o <<= 1) {
        int x = (t >= o) ? ps[t - o] : 0;
        __syncthreads();
        ps[t] += x;
        __syncthreads();
    }
    int run = (t > 0) ? ps[t - 1] : 0;
    for (int i = 0; i < SEG; ++i) {
        int idx = base + i;
        if (idx < NBK) {
            bptr[idx] = run;
            run += cnt[i];
        }
    }
    if (t == 255) bptr[NBK] = ps[255];
}

// ---------------------------------------------------------------------------
// Phase B2: per-(chunk-block, bucket) offsets. One wave per bucket.
// ---------------------------------------------------------------------------
__global__ __launch_bounds__(64) void k_boff(const int* __restrict__ bcnt,
                                             const int* __restrict__ bptr,
                                             int* __restrict__ boff, int NBK) {
    const int b = blockIdx.x;           // bucket
    const int l = threadIdx.x;          // lane, owns chunk blocks 4l..4l+3
    int c0 = bcnt[(size_t)(4 * l + 0) * NBK + b];
    int c1 = bcnt[(size_t)(4 * l + 1) * NBK + b];
    int c2 = bcnt[(size_t)(4 * l + 2) * NBK + b];
    int c3 = bcnt[(size_t)(4 * l + 3) * NBK + b];
    int s = c0 + c1 + c2 + c3;
    int ps = s;
    for (int o = 1; o < 64; o <<= 1) {
        int x = __shfl_up(ps, o);
        if (l >= o) ps += x;
    }
    int base = bptr[b] + (ps - s);      // exclusive prefix
    boff[(size_t)(4 * l + 0) * NBK + b] = base;
    boff[(size_t)(4 * l + 1) * NBK + b] = base + c0;
    boff[(size_t)(4 * l + 2) * NBK + b] = base + c0 + c1;
    boff[(size_t)(4 * l + 3) * NBK + b] = base + c0 + c1 + c2;
}

// ---------------------------------------------------------------------------
// Phase C: single-pass scatter. LDS cursors preloaded from boff.
// entry: x = (row_local << 17) | col ; y = f32 edge value
// ---------------------------------------------------------------------------
__global__ __launch_bounds__(1024) void k_bscat(const int* __restrict__ er,
                                                const int* __restrict__ ec,
                                                const float* __restrict__ ev,
                                                const int* __restrict__ boff,
                                                int2* __restrict__ packed0,
                                                int E, int NBK, int chunk) {
    __shared__ int lh[NBK_MAX];
    const int t = threadIdx.x;
    const int* brow = boff + (size_t)blockIdx.x * NBK;
    for (int k = t; k < NBK; k += 1024) lh[k] = brow[k];   // coalesced
    __syncthreads();
    const int s0 = blockIdx.x * chunk;          // multiple of 4
    const int s1 = min(E, s0 + chunk);
    for (int i = s0 + t * 4; i < s1; i += 4096) {
        if (i + 3 < s1) {
            int4 r = *(const int4*)(er + i);
            int4 c = *(const int4*)(ec + i);
            float4 v = *(const float4*)(ev + i);
            int bkt, slot;
            bkt = r.x >> 6; slot = atomicAdd(&lh[bkt], 1);
            packed0[slot] = make_int2(((r.x & 63) << 17) | c.x, __float_as_int(v.x));
            bkt = r.y >> 6; slot = atomicAdd(&lh[bkt], 1);
            packed0[slot] = make_int2(((r.y & 63) << 17) | c.y, __float_as_int(v.y));
            bkt = r.z >> 6; slot = atomicAdd(&lh[bkt], 1);
            packed0[slot] = make_int2(((r.z & 63) << 17) | c.z, __float_as_int(v.z));
            bkt = r.w >> 6; slot = atomicAdd(&lh[bkt], 1);
            packed0[slot] = make_int2(((r.w & 63) << 17) | c.w, __float_as_int(v.w));
        } else {
            for (int q = i; q < s1; ++q) {
                int r = er[q];
                int bkt = r >> 6;
                int slot = atomicAdd(&lh[bkt], 1);
                packed0[slot] = make_int2(((r & 63) << 17) | ec[q], __float_as_int(ev[q]));
            }
        }
    }
}

// ---------------------------------------------------------------------------
// Fused regroup + aggregate: one 512-thread block (8 waves) per bucket.
// 1) stage bucket entries into registers (<=4/thread), count per node in LDS
// 2) prefix over 64 node counters
// 3) permute entries into sorted LDS buffer (per-node contiguous)
// 4) wave w aggregates nodes w*8..w*8+7: metadata via broadcast ds_read,
//    4 independent uint2 gathers in flight per 32-lane half.
// ---------------------------------------------------------------------------
__global__ __launch_bounds__(512) void k_bagg2(const uint* __restrict__ Hb,
                                               const int* __restrict__ bptr,
                                               const int2* __restrict__ packed0,
                                               const float* __restrict__ bias,
                                               float* __restrict__ out, int N) {
    __shared__ int2 srt[SCAP];
    __shared__ int lcnt[NPB];
    __shared__ int lpref[NPB];
    __shared__ int lcur[NPB];
    const int t = threadIdx.x;
    const int b = blockIdx.x;
    if (t < NPB) { lcnt[t] = 0; lcur[t] = 0; }
    __syncthreads();

    const int s = bptr[b], e = bptr[b + 1];
    const int cnt = e - s;
    const int staged = min(cnt, SCAP);

    // phase 1: load + count (entries kept in registers)
    int2 myent[4];
#pragma unroll
    for (int k = 0; k < 4; ++k) {
        const int i = t + k * 512;
        myent[k] = make_int2(0, 0);
        if (i < staged) {
            myent[k] = packed0[s + i];
            atomicAdd(&lcnt[((uint)myent[k].x) >> 17], 1);
        }
    }
    __syncthreads();

    // phase 2: exclusive prefix over 64 counters
    if (t < NPB) {
        int p = 0;
        for (int k = 0; k < t; ++k) p += lcnt[k];
        lpref[t] = p;
    }
    __syncthreads();

    // phase 3: permute into sorted LDS buffer
#pragma unroll
    for (int k = 0; k < 4; ++k) {
        const int i = t + k * 512;
        if (i < staged) {
            const int rl = ((uint)myent[k].x) >> 17;
            const int pos = lpref[rl] + atomicAdd(&lcur[rl], 1);
            srt[pos] = make_int2(myent[k].x & 0x1FFFF, myent[k].y);
        }
    }
    __syncthreads();

    // phase 4: aggregate; wave w -> nodes [w*8, w*8+8)
    const int wid = t >> 6, lane = t & 63;
    const int h = lane >> 5, sl = lane & 31;
    const float4 bv = ((const float4*)bias)[sl];

    for (int r = wid * 8; r < wid * 8 + 8; ++r) {
        const int node = b * NPB + r;
        if (node >= N) continue;
        const int m = lcnt[r], p0 = lpref[r];
        float4 acc = make_float4(0.f, 0.f, 0.f, 0.f);
        int jj = h;
        for (; jj + 6 < m; jj += 8) {
            const int2 e0 = srt[p0 + jj];
            const int2 e1 = srt[p0 + jj + 2];
            const int2 e2 = srt[p0 + jj + 4];
            const int2 e3 = srt[p0 + jj + 6];
            const uint2 g0 = ((const uint2*)(Hb + (size_t)e0.x * 64))[sl];
            const uint2 g1 = ((const uint2*)(Hb + (size_t)e1.x * 64))[sl];
            const uint2 g2 = ((const uint2*)(Hb + (size_t)e2.x * 64))[sl];
            const uint2 g3 = ((const uint2*)(Hb + (size_t)e3.x * 64))[sl];
            const float v0 = __int_as_float(e0.y);
            const float v1 = __int_as_float(e1.y);
            const float v2 = __int_as_float(e2.y);
            const float v3 = __int_as_float(e3.y);
            acc.x = fmaf(v0, __uint_as_float(g0.x << 16), acc.x);
            acc.y = fmaf(v0, __uint_as_float(g0.x & 0xffff0000u), acc.y);
            acc.z = fmaf(v0, __uint_as_float(g0.y << 16), acc.z);
            acc.w = fmaf(v0, __uint_as_float(g0.y & 0xffff0000u), acc.w);
            acc.x = fmaf(v1, __uint_as_float(g1.x << 16), acc.x);
            acc.y = fmaf(v1, __uint_as_float(g1.x & 0xffff0000u), acc.y);
            acc.z = fmaf(v1, __uint_as_float(g1.y << 16), acc.z);
            acc.w = fmaf(v1, __uint_as_float(g1.y & 0xffff0000u), acc.w);
            acc.x = fmaf(v2, __uint_as_float(g2.x << 16), acc.x);
            acc.y = fmaf(v2, __uint_as_float(g2.x & 0xffff0000u), acc.y);
            acc.z = fmaf(v2, __uint_as_float(g2.y << 16), acc.z);
            acc.w = fmaf(v2, __uint_as_float(g2.y & 0xffff0000u), acc.w);
            acc.x = fmaf(v3, __uint_as_float(g3.x << 16), acc.x);
            acc.y = fmaf(v3, __uint_as_float(g3.x & 0xffff0000u), acc.y);
            acc.z = fmaf(v3, __uint_as_float(g3.y << 16), acc.z);
            acc.w = fmaf(v3, __uint_as_float(g3.y & 0xffff0000u), acc.w);
        }
        for (; jj < m; jj += 2) {
            const int2 e0 = srt[p0 + jj];
            const uint2 g0 = ((const uint2*)(Hb + (size_t)e0.x * 64))[sl];
            const float v0 = __int_as_float(e0.y);
            acc.x = fmaf(v0, __uint_as_float(g0.x << 16), acc.x);
            acc.y = fmaf(v0, __uint_as_float(g0.x & 0xffff0000u), acc.y);
            acc.z = fmaf(v0, __uint_as_float(g0.y << 16), acc.z);
            acc.w = fmaf(v0, __uint_as_float(g0.y & 0xffff0000u), acc.w);
        }
        // overflow (cnt > SCAP): rare slow path, h==0 half only
        for (int i = staged; i < cnt; ++i) {
            const int2 en = packed0[s + i];
            if ((int)(((uint)en.x) >> 17) == r && h == 0) {
                const int col = en.x & 0x1FFFF;
                const float v = __int_as_float(en.y);
                const uint2 g = ((const uint2*)(Hb + (size_t)col * 64))[sl];
                acc.x = fmaf(v, __uint_as_float(g.x << 16), acc.x);
                acc.y = fmaf(v, __uint_as_float(g.x & 0xffff0000u), acc.y);
                acc.z = fmaf(v, __uint_as_float(g.y << 16), acc.z);
                acc.w = fmaf(v, __uint_as_float(g.y & 0xffff0000u), acc.w);
            }
        }
        acc.x += __shfl_xor(acc.x, 32);
        acc.y += __shfl_xor(acc.y, 32);
        acc.z += __shfl_xor(acc.z, 32);
        acc.w += __shfl_xor(acc.w, 32);
        if (h == 0) {
            float4 o;
            o.x = acc.x + bv.x; o.y = acc.y + bv.y;
            o.z = acc.z + bv.z; o.w = acc.w + bv.w;
            o.x = o.x >= 0.f ? o.x : NEG_SLOPE * o.x;
            o.y = o.y >= 0.f ? o.y : NEG_SLOPE * o.y;
            o.z = o.z >= 0.f ? o.z : NEG_SLOPE * o.z;
            o.w = o.w >= 0.f ? o.w : NEG_SLOPE * o.w;
            ((float4*)(out + (size_t)node * DMODEL))[sl] = o;
        }
    }
}

// ---------------------------------------------------------------------------
extern "C" void kernel_launch(void* const* d_in, const int* in_sizes, int n_in,
                              void* d_out, int out_size, void* d_ws, size_t ws_size,
                              hipStream_t stream) {
    const float* X    = (const float*)d_in[0];
    const int*   er   = (const int*)d_in[1];
    const int*   ec   = (const int*)d_in[2];
    const float* ev   = (const float*)d_in[3];
    const float* W    = (const float*)d_in[4];
    const float* bias = (const float*)d_in[5];
    float* out = (float*)d_out;

    const int N = in_sizes[0] / DMODEL;
    const int E = in_sizes[1];
    const int NBK = (N + NPB - 1) / NPB;   // 1563 for N=100000 (<= NBK_MAX)

    // workspace layout (128B-aligned slabs)
    char* ws = (char*)d_ws;
    size_t off = 0;
    auto alloc = [&](size_t bytes) {
        void* p = ws + off;
        off += (bytes + 127) & ~(size_t)127;
        return p;
    };
    ushort_t* H   = (ushort_t*)alloc((size_t)N * DMODEL * sizeof(ushort_t));
    ushort_t* Wt  = (ushort_t*)alloc((size_t)DMODEL * DMODEL * sizeof(ushort_t));
    int* gcnt_p   = (int*)alloc((size_t)NBK * CPAD * sizeof(int));
    int* bptr     = (int*)alloc((size_t)(NBK + 1) * sizeof(int));
    int* bcnt     = (int*)alloc((size_t)NBLK * NBK * sizeof(int));
    int* boff     = (int*)alloc((size_t)NBLK * NBK * sizeof(int));
    int2* packed0 = (int2*)alloc((size_t)(E + 4) * sizeof(int2));
    (void)ws_size;

    const int ztot = NBK * CPAD;

    // 1) setup (Wt + zero gcnt), then MFMA GEMM (f32 in, bf16 out)
    hipLaunchKernelGGL(k_setup, dim3(64 + (ztot + 255) / 256), dim3(256), 0, stream,
                       W, Wt, gcnt_p, ztot);
    const int gemm_blocks = (N + 63) / 64;           // 4 waves x 16 rows per block
    hipLaunchKernelGGL(k_gemm, dim3(gemm_blocks), dim3(256), 0, stream, X, Wt, H, N);

    // 2) bucket grouping (single-pass scatter via stored counts)
    const int chunk = ((((E + NBLK - 1) / NBLK) + 3) & ~3);   // multiple of 4
    hipLaunchKernelGGL(k_bhist, dim3(NBLK), dim3(1024), 0, stream,
                       er, gcnt_p, bcnt, E, NBK, chunk);
    hipLaunchKernelGGL(k_bscan, dim3(1), dim3(256), 0, stream, gcnt_p, bptr, NBK);
    hipLaunchKernelGGL(k_boff,  dim3(NBK), dim3(64), 0, stream, bcnt, bptr, boff, NBK);
    hipLaunchKernelGGL(k_bscat, dim3(NBLK), dim3(1024), 0, stream,
                       er, ec, ev, boff, packed0, E, NBK, chunk);

    // 3) fused regroup + aggregate, one block per bucket
    hipLaunchKernelGGL(k_bagg2, dim3(NBK), dim3(512), 0, stream,
                       (const uint*)H, bptr, packed0, bias, out, N);
}

// Round 9
// 149.634 us; speedup vs baseline: 8.7476x; 1.0907x over previous
//
#include <hip/hip_runtime.h>

#define DMODEL 128
#define NEG_SLOPE 0.01f
#define NPB 64              // nodes per bucket
#define NBK_MAX 1600        // max buckets supported by LDS arrays (N <= 102400)
#define CPAD 16             // counter padding (ints) -> one counter per 64B line
#define SBLK 256            // scatter blocks in fused kernel
#define CAP 1536            // static slab capacity per bucket (mean 1024 + 16 sigma)
#define OCAP 65536          // overflow spill capacity (entries)

typedef unsigned int uint;
typedef unsigned short ushort_t;
typedef __attribute__((ext_vector_type(8))) short short8v;   // 8 bf16 (4 VGPRs)
typedef __attribute__((ext_vector_type(4))) float float4v;   // MFMA acc

// round-to-nearest-even f32 -> bf16
__device__ inline ushort_t f2bf(float f) {
    uint u = __float_as_uint(f);
    u += 0x7FFFu + ((u >> 16) & 1u);
    return (ushort_t)(u >> 16);
}

// ---------------------------------------------------------------------------
// Pre: blocks 0..63 build Wt[c][k] = bf16(W[k][c]); the rest zero cur + ocnt.
// Must be its own dispatch: provides happens-before for the scat cursors.
// ---------------------------------------------------------------------------
__global__ __launch_bounds__(256) void k_pre(const float* __restrict__ W,
                                             ushort_t* __restrict__ Wt,
                                             int* __restrict__ cur,   // NBK*CPAD ints, then ocnt
                                             int ztot) {
    const int b = blockIdx.x;
    if (b < 64) {
        const int t = b * 256 + threadIdx.x;          // 16384 threads
        const int k = t >> 7, c = t & 127;
        Wt[(size_t)c * DMODEL + k] = f2bf(W[(size_t)k * DMODEL + c]);
    } else {
        const int i = (b - 64) * 256 + threadIdx.x;
        if (i < ztot) cur[i] = 0;
    }
}

// ---------------------------------------------------------------------------
// Fused scatter + GEMM (independent work, co-resident for overlap).
// blocks [0, SBLK): bucket-scatter of edges into static slabs.
// blocks [SBLK, ..): MFMA GEMM, 16 waves x 16 rows per block.
// ---------------------------------------------------------------------------
__global__ __launch_bounds__(1024) void k_fused(
        // scat inputs
        const int* __restrict__ er, const int* __restrict__ ec,
        const float* __restrict__ ev, int* __restrict__ cur,
        int* __restrict__ ocnt, int4* __restrict__ ovf,
        int2* __restrict__ packed0, int E, int NBK, int chunk,
        // gemm inputs
        const float* __restrict__ X, const ushort_t* __restrict__ Wt,
        ushort_t* __restrict__ H, int N) {
    __shared__ int lh[NBK_MAX];
    __shared__ int lb[NBK_MAX];
    const int t = threadIdx.x;

    if (blockIdx.x < SBLK) {
        // ---------------- scatter branch ----------------
        for (int k = t; k < NBK; k += 1024) lh[k] = 0;
        __syncthreads();
        const int s0 = blockIdx.x * chunk;          // chunk multiple of 4
        const int s1 = min(E, s0 + chunk);
        // pass 1: count
        for (int i = s0 + t * 4; i < s1; i += 4096) {
            if (i + 3 < s1) {
                int4 r = *(const int4*)(er + i);
                atomicAdd(&lh[r.x >> 6], 1);
                atomicAdd(&lh[r.y >> 6], 1);
                atomicAdd(&lh[r.z >> 6], 1);
                atomicAdd(&lh[r.w >> 6], 1);
            } else {
                for (int q = i; q < s1; ++q) atomicAdd(&lh[er[q] >> 6], 1);
            }
        }
        __syncthreads();
        // reserve disjoint ranges (global atomic per (block,bucket))
        for (int k = t; k < NBK; k += 1024) {
            int c = lh[k];
            lb[k] = c ? atomicAdd(&cur[k * CPAD], c) : 0;
            lh[k] = 0;   // reuse as local cursor
        }
        __syncthreads();
        // pass 2: scatter
        for (int i = s0 + t * 4; i < s1; i += 4096) {
            if (i + 3 < s1) {
                int4 r = *(const int4*)(er + i);
                int4 c = *(const int4*)(ec + i);
                float4 v = *(const float4*)(ev + i);
                int bkt, rl, slot;
#define SCAT1(RR, CC, VV)                                                     \
                bkt = (RR) >> 6; rl = (RR) & 63;                              \
                slot = lb[bkt] + atomicAdd(&lh[bkt], 1);                      \
                if (slot < CAP)                                               \
                    packed0[(size_t)bkt * CAP + slot] =                       \
                        make_int2((rl << 17) | (CC), __float_as_int(VV));     \
                else {                                                        \
                    int o = atomicAdd(ocnt, 1);                               \
                    if (o < OCAP) ovf[o] = make_int4(bkt, rl, (CC), __float_as_int(VV)); \
                }
                SCAT1(r.x, c.x, v.x)
                SCAT1(r.y, c.y, v.y)
                SCAT1(r.z, c.z, v.z)
                SCAT1(r.w, c.w, v.w)
            } else {
                for (int q = i; q < s1; ++q) {
                    int rr = er[q];
                    int bkt = rr >> 6, rl = rr & 63;
                    int slot = lb[bkt] + atomicAdd(&lh[bkt], 1);
                    if (slot < CAP)
                        packed0[(size_t)bkt * CAP + slot] =
                            make_int2((rl << 17) | ec[q], __float_as_int(ev[q]));
                    else {
                        int o = atomicAdd(ocnt, 1);
                        if (o < OCAP) ovf[o] = make_int4(bkt, rl, ec[q], __float_as_int(ev[q]));
                    }
                }
            }
        }
    } else {
        // ---------------- GEMM branch (MFMA, no LDS) ----------------
        const int gb = blockIdx.x - SBLK;
        const int wid = t >> 6, lane = t & 63;
        const int wrow = (gb * 16 + wid) * 16;       // 16 rows per wave
        if (wrow >= N) return;
        const int lr = lane & 15;
        const int kg = lane >> 4;

        const float* xrow = X + (size_t)(wrow + lr) * DMODEL + kg * 8;
        const ushort_t* wtb = Wt + (size_t)lr * DMODEL + kg * 8;

        float4v acc[8] = {};
#pragma unroll
        for (int s = 0; s < 4; ++s) {                // k-steps of 32
            float4 x0 = *(const float4*)(xrow + s * 32);
            float4 x1 = *(const float4*)(xrow + s * 32 + 4);
            short8v af;
            af[0] = (short)f2bf(x0.x); af[1] = (short)f2bf(x0.y);
            af[2] = (short)f2bf(x0.z); af[3] = (short)f2bf(x0.w);
            af[4] = (short)f2bf(x1.x); af[5] = (short)f2bf(x1.y);
            af[6] = (short)f2bf(x1.z); af[7] = (short)f2bf(x1.w);
#pragma unroll
            for (int c = 0; c < 8; ++c) {
                short8v bf = *(const short8v*)(wtb + (size_t)c * 16 * DMODEL + s * 32);
                acc[c] = __builtin_amdgcn_mfma_f32_16x16x32_bf16(af, bf, acc[c], 0, 0, 0);
            }
        }
#pragma unroll
        for (int c = 0; c < 8; ++c) {
#pragma unroll
            for (int r = 0; r < 4; ++r) {
                const int row = wrow + kg * 4 + r;
                H[(size_t)row * DMODEL + c * 16 + lr] = f2bf(acc[c][r]);
            }
        }
    }
}

// ---------------------------------------------------------------------------
// Fused regroup + aggregate: one 256-thread block (4 waves) per bucket.
// Slab base is static (b*CAP); count from cur. Phase 4: wave w -> 16 nodes,
// half-wave edge pairs, 4 independent uint2 gathers in flight per half.
// ---------------------------------------------------------------------------
__global__ __launch_bounds__(256) void k_bagg2(const uint* __restrict__ Hb,
                                               const int* __restrict__ cur,
                                               const int* __restrict__ ocnt,
                                               const int4* __restrict__ ovf,
                                               const int2* __restrict__ packed0,
                                               const float* __restrict__ bias,
                                               float* __restrict__ out, int N) {
    __shared__ int2 srt[CAP];
    __shared__ int lcnt[NPB];
    __shared__ int lpref[NPB];
    __shared__ int lcur[NPB];
    const int t = threadIdx.x;
    const int b = blockIdx.x;
    if (t < NPB) { lcnt[t] = 0; lcur[t] = 0; }
    __syncthreads();

    const int cnt = cur[b * CPAD];
    const int staged = min(cnt, CAP);
    const int2* slab = packed0 + (size_t)b * CAP;

    // phase 1: load + count (entries kept in registers)
    int2 myent[6];
#pragma unroll
    for (int k = 0; k < 6; ++k) {
        const int i = t + k * 256;
        myent[k] = make_int2(0, 0);
        if (i < staged) {
            myent[k] = slab[i];
            atomicAdd(&lcnt[((uint)myent[k].x) >> 17], 1);
        }
    }
    __syncthreads();

    // phase 2: exclusive prefix over 64 counters
    if (t < NPB) {
        int p = 0;
        for (int k = 0; k < t; ++k) p += lcnt[k];
        lpref[t] = p;
    }
    __syncthreads();

    // phase 3: permute into per-node-contiguous LDS buffer
#pragma unroll
    for (int k = 0; k < 6; ++k) {
        const int i = t + k * 256;
        if (i < staged) {
            const int rl = ((uint)myent[k].x) >> 17;
            const int pos = lpref[rl] + atomicAdd(&lcur[rl], 1);
            srt[pos] = make_int2(myent[k].x & 0x1FFFF, myent[k].y);
        }
    }
    __syncthreads();

    // phase 4: aggregate; wave w -> nodes [w*16, w*16+16)
    const int wid = t >> 6, lane = t & 63;
    const int h = lane >> 5, sl = lane & 31;
    const float4 bv = ((const float4*)bias)[sl];
    const int oc = min(*ocnt, OCAP);

    for (int r = wid * 16; r < wid * 16 + 16; ++r) {
        const int node = b * NPB + r;
        if (node >= N) continue;
        const int m = lcnt[r], p0 = lpref[r];
        float4 acc = make_float4(0.f, 0.f, 0.f, 0.f);
        int jj = h;
        for (; jj + 6 < m; jj += 8) {
            const int2 e0 = srt[p0 + jj];
            const int2 e1 = srt[p0 + jj + 2];
            const int2 e2 = srt[p0 + jj + 4];
            const int2 e3 = srt[p0 + jj + 6];
            const uint2 g0 = ((const uint2*)(Hb + (size_t)e0.x * 64))[sl];
            const uint2 g1 = ((const uint2*)(Hb + (size_t)e1.x * 64))[sl];
            const uint2 g2 = ((const uint2*)(Hb + (size_t)e2.x * 64))[sl];
            const uint2 g3 = ((const uint2*)(Hb + (size_t)e3.x * 64))[sl];
            const float v0 = __int_as_float(e0.y);
            const float v1 = __int_as_float(e1.y);
            const float v2 = __int_as_float(e2.y);
            const float v3 = __int_as_float(e3.y);
            acc.x = fmaf(v0, __uint_as_float(g0.x << 16), acc.x);
            acc.y = fmaf(v0, __uint_as_float(g0.x & 0xffff0000u), acc.y);
            acc.z = fmaf(v0, __uint_as_float(g0.y << 16), acc.z);
            acc.w = fmaf(v0, __uint_as_float(g0.y & 0xffff0000u), acc.w);
            acc.x = fmaf(v1, __uint_as_float(g1.x << 16), acc.x);
            acc.y = fmaf(v1, __uint_as_float(g1.x & 0xffff0000u), acc.y);
            acc.z = fmaf(v1, __uint_as_float(g1.y << 16), acc.z);
            acc.w = fmaf(v1, __uint_as_float(g1.y & 0xffff0000u), acc.w);
            acc.x = fmaf(v2, __uint_as_float(g2.x << 16), acc.x);
            acc.y = fmaf(v2, __uint_as_float(g2.x & 0xffff0000u), acc.y);
            acc.z = fmaf(v2, __uint_as_float(g2.y << 16), acc.z);
            acc.w = fmaf(v2, __uint_as_float(g2.y & 0xffff0000u), acc.w);
            acc.x = fmaf(v3, __uint_as_float(g3.x << 16), acc.x);
            acc.y = fmaf(v3, __uint_as_float(g3.x & 0xffff0000u), acc.y);
            acc.z = fmaf(v3, __uint_as_float(g3.y << 16), acc.z);
            acc.w = fmaf(v3, __uint_as_float(g3.y & 0xffff0000u), acc.w);
        }
        for (; jj < m; jj += 2) {
            const int2 e0 = srt[p0 + jj];
            const uint2 g0 = ((const uint2*)(Hb + (size_t)e0.x * 64))[sl];
            const float v0 = __int_as_float(e0.y);
            acc.x = fmaf(v0, __uint_as_float(g0.x << 16), acc.x);
            acc.y = fmaf(v0, __uint_as_float(g0.x & 0xffff0000u), acc.y);
            acc.z = fmaf(v0, __uint_as_float(g0.y << 16), acc.z);
            acc.w = fmaf(v0, __uint_as_float(g0.y & 0xffff0000u), acc.w);
        }
        // overflow spill (normally oc == 0)
        for (int i = 0; i < oc; ++i) {
            const int4 o4 = ovf[i];
            if (o4.x == b && o4.y == r && h == 0) {
                const float v = __int_as_float(o4.w);
                const uint2 g = ((const uint2*)(Hb + (size_t)o4.z * 64))[sl];
                acc.x = fmaf(v, __uint_as_float(g.x << 16), acc.x);
                acc.y = fmaf(v, __uint_as_float(g.x & 0xffff0000u), acc.y);
                acc.z = fmaf(v, __uint_as_float(g.y << 16), acc.z);
                acc.w = fmaf(v, __uint_as_float(g.y & 0xffff0000u), acc.w);
            }
        }
        acc.x += __shfl_xor(acc.x, 32);
        acc.y += __shfl_xor(acc.y, 32);
        acc.z += __shfl_xor(acc.z, 32);
        acc.w += __shfl_xor(acc.w, 32);
        if (h == 0) {
            float4 o;
            o.x = acc.x + bv.x; o.y = acc.y + bv.y;
            o.z = acc.z + bv.z; o.w = acc.w + bv.w;
            o.x = o.x >= 0.f ? o.x : NEG_SLOPE * o.x;
            o.y = o.y >= 0.f ? o.y : NEG_SLOPE * o.y;
            o.z = o.z >= 0.f ? o.z : NEG_SLOPE * o.z;
            o.w = o.w >= 0.f ? o.w : NEG_SLOPE * o.w;
            ((float4*)(out + (size_t)node * DMODEL))[sl] = o;
        }
    }
}

// ---------------------------------------------------------------------------
extern "C" void kernel_launch(void* const* d_in, const int* in_sizes, int n_in,
                              void* d_out, int out_size, void* d_ws, size_t ws_size,
                              hipStream_t stream) {
    const float* X    = (const float*)d_in[0];
    const int*   er   = (const int*)d_in[1];
    const int*   ec   = (const int*)d_in[2];
    const float* ev   = (const float*)d_in[3];
    const float* W    = (const float*)d_in[4];
    const float* bias = (const float*)d_in[5];
    float* out = (float*)d_out;

    const int N = in_sizes[0] / DMODEL;
    const int E = in_sizes[1];
    const int NBK = (N + NPB - 1) / NPB;   // 1563 for N=100000 (<= NBK_MAX)

    // workspace layout (128B-aligned slabs)
    char* ws = (char*)d_ws;
    size_t off = 0;
    auto alloc = [&](size_t bytes) {
        void* p = ws + off;
        off += (bytes + 127) & ~(size_t)127;
        return p;
    };
    ushort_t* H   = (ushort_t*)alloc((size_t)N * DMODEL * sizeof(ushort_t));
    ushort_t* Wt  = (ushort_t*)alloc((size_t)DMODEL * DMODEL * sizeof(ushort_t));
    int* cur      = (int*)alloc(((size_t)NBK * CPAD + 1) * sizeof(int));  // +ocnt
    int* ocnt     = cur + (size_t)NBK * CPAD;
    int4* ovf     = (int4*)alloc((size_t)OCAP * sizeof(int4));
    int2* packed0 = (int2*)alloc((size_t)NBK * CAP * sizeof(int2));
    (void)ws_size;

    const int ztot = NBK * CPAD + 1;

    // 1) pre: Wt transpose + zero cursors (happens-before for fused scat)
    hipLaunchKernelGGL(k_pre, dim3(64 + (ztot + 255) / 256), dim3(256), 0, stream,
                       W, Wt, cur, ztot);

    // 2) fused scatter (blocks 0..SBLK-1) + GEMM (the rest)
    const int chunk = ((((E + SBLK - 1) / SBLK) + 3) & ~3);   // multiple of 4
    const int gemm_blocks = (N + 255) / 256;                  // 16 waves x 16 rows
    hipLaunchKernelGGL(k_fused, dim3(SBLK + gemm_blocks), dim3(1024), 0, stream,
                       er, ec, ev, cur, ocnt, ovf, packed0, E, NBK, chunk,
                       X, Wt, H, N);

    // 3) fused regroup + aggregate, one 256-thread block per bucket
    hipLaunchKernelGGL(k_bagg2, dim3(NBK), dim3(256), 0, stream,
                       (const uint*)H, cur, ocnt, ovf, packed0, bias, out, N);
}

// Round 10
// 149.156 us; speedup vs baseline: 8.7757x; 1.0032x over previous
//
#include <hip/hip_runtime.h>

#define DMODEL 128
#define NEG_SLOPE 0.01f
#define NPB 64              // nodes per bucket
#define NBK_MAX 1600        // max buckets supported by LDS arrays (N <= 102400)
#define CPAD 16             // counter padding (ints) -> one counter per 64B line
#define SBLK 256            // scatter blocks
#define CAP 1536            // static slab capacity per bucket (mean 1024 + 16 sigma)
#define OCAP 65536          // overflow spill capacity (entries)

typedef unsigned int uint;
typedef unsigned short ushort_t;
typedef __attribute__((ext_vector_type(8))) short short8v;   // 8 bf16 (4 VGPRs)
typedef __attribute__((ext_vector_type(4))) float float4v;   // MFMA acc

// round-to-nearest-even f32 -> bf16
__device__ inline ushort_t f2bf(float f) {
    uint u = __float_as_uint(f);
    u += 0x7FFFu + ((u >> 16) & 1u);
    return (ushort_t)(u >> 16);
}

// ---------------------------------------------------------------------------
// Pre: blocks 0..63 build Wt[c][k] = bf16(W[k][c]); the rest zero cur + ocnt.
// ---------------------------------------------------------------------------
__global__ __launch_bounds__(256) void k_pre(const float* __restrict__ W,
                                             ushort_t* __restrict__ Wt,
                                             int* __restrict__ cur,   // NBK*CPAD ints, then ocnt
                                             int ztot) {
    const int b = blockIdx.x;
    if (b < 64) {
        const int t = b * 256 + threadIdx.x;          // 16384 threads
        const int k = t >> 7, c = t & 127;
        Wt[(size_t)c * DMODEL + k] = f2bf(W[(size_t)k * DMODEL + c]);
    } else {
        const int i = (b - 64) * 256 + threadIdx.x;
        if (i < ztot) cur[i] = 0;
    }
}

// ---------------------------------------------------------------------------
// GEMM v2: H(bf16) = bf16(X) @ bf16(W). 256 threads / 64 rows per block.
// X tile staged COALESCED into LDS as bf16 with XOR-swizzled 16B chunks
// (chunk ^= row&7) so A-fragment ds_read_b128 is ~conflict-free.
// B-frags from L1-hot global Wt. C/D: col=lane&15, row=(lane>>4)*4+reg.
// ---------------------------------------------------------------------------
__global__ __launch_bounds__(256) void k_gemm(const float* __restrict__ X,
                                              const ushort_t* __restrict__ Wt,
                                              ushort_t* __restrict__ H, int N) {
    __shared__ ushort_t Xs[64 * 128];   // 16 KB, [row][swizzled 16B chunks]
    const int t = threadIdx.x;
    const int row0 = blockIdx.x * 64;

    // stage: 2048 float4 (64 rows x 32 f4), 8 per thread, contiguous per wave
#pragma unroll
    for (int i = 0; i < 8; ++i) {
        const int f = t + i * 256;      // 0..2047
        const int r = f >> 5;           // row in tile
        const int c4 = f & 31;          // float4 index within row
        float4 v = make_float4(0.f, 0.f, 0.f, 0.f);
        if (row0 + r < N) v = *(const float4*)(X + (size_t)(row0 + r) * DMODEL + c4 * 4);
        ushort4 u;
        u.x = f2bf(v.x); u.y = f2bf(v.y); u.z = f2bf(v.z); u.w = f2bf(v.w);
        const int chunk = (c4 >> 1) ^ (r & 7);          // swizzled 16B chunk
        *(ushort4*)(Xs + r * 128 + chunk * 8 + (c4 & 1) * 4) = u;
    }
    __syncthreads();

    const int wid = t >> 6, lane = t & 63;
    const int lr = lane & 15;           // A-row / B-col / C-col in 16x16 tile
    const int kg = lane >> 4;           // k-group 0..3
    const int wr = wid * 16 + lr;       // A row within tile ((wid*16)&7==0 -> row&7==lr&7)
    const ushort_t* wtb = Wt + (size_t)lr * DMODEL + kg * 8;

    float4v acc[8] = {};                // 8 col-tiles x 4 f32
#pragma unroll
    for (int s = 0; s < 4; ++s) {       // k-steps of 32
        const int chunk = (s * 4 + kg) ^ (lr & 7);
        const short8v af = *(const short8v*)(Xs + wr * 128 + chunk * 8);
#pragma unroll
        for (int c = 0; c < 8; ++c) {
            const short8v bf = *(const short8v*)(wtb + (size_t)c * 16 * DMODEL + s * 32);
            acc[c] = __builtin_amdgcn_mfma_f32_16x16x32_bf16(af, bf, acc[c], 0, 0, 0);
        }
    }

    // epilogue: H[row0 + wid*16 + kg*4 + r][c*16 + lr]
#pragma unroll
    for (int c = 0; c < 8; ++c) {
#pragma unroll
        for (int r = 0; r < 4; ++r) {
            const int row = row0 + wid * 16 + kg * 4 + r;
            if (row < N) H[(size_t)row * DMODEL + c * 16 + lr] = f2bf(acc[c][r]);
        }
    }
}

// ---------------------------------------------------------------------------
// Scatter (two-pass, standalone): count -> reserve slab ranges -> scatter.
// entry: x = (row_local << 17) | col ; y = f32 edge value
// ---------------------------------------------------------------------------
__global__ __launch_bounds__(1024) void k_scat(const int* __restrict__ er,
                                               const int* __restrict__ ec,
                                               const float* __restrict__ ev,
                                               int* __restrict__ cur,
                                               int* __restrict__ ocnt,
                                               int4* __restrict__ ovf,
                                               int2* __restrict__ packed0,
                                               int E, int NBK, int chunk) {
    __shared__ int lh[NBK_MAX];
    __shared__ int lb[NBK_MAX];
    const int t = threadIdx.x;
    for (int k = t; k < NBK; k += 1024) lh[k] = 0;
    __syncthreads();
    const int s0 = blockIdx.x * chunk;          // chunk multiple of 4
    const int s1 = min(E, s0 + chunk);
    // pass 1: count
    for (int i = s0 + t * 4; i < s1; i += 4096) {
        if (i + 3 < s1) {
            int4 r = *(const int4*)(er + i);
            atomicAdd(&lh[r.x >> 6], 1);
            atomicAdd(&lh[r.y >> 6], 1);
            atomicAdd(&lh[r.z >> 6], 1);
            atomicAdd(&lh[r.w >> 6], 1);
        } else {
            for (int q = i; q < s1; ++q) atomicAdd(&lh[er[q] >> 6], 1);
        }
    }
    __syncthreads();
    // reserve disjoint ranges
    for (int k = t; k < NBK; k += 1024) {
        int c = lh[k];
        lb[k] = c ? atomicAdd(&cur[k * CPAD], c) : 0;
        lh[k] = 0;   // reuse as local cursor
    }
    __syncthreads();
    // pass 2: scatter
    for (int i = s0 + t * 4; i < s1; i += 4096) {
        if (i + 3 < s1) {
            int4 r = *(const int4*)(er + i);
            int4 c = *(const int4*)(ec + i);
            float4 v = *(const float4*)(ev + i);
            int bkt, rl, slot;
#define SCAT1(RR, CC, VV)                                                     \
            bkt = (RR) >> 6; rl = (RR) & 63;                                  \
            slot = lb[bkt] + atomicAdd(&lh[bkt], 1);                          \
            if (slot < CAP)                                                   \
                packed0[(size_t)bkt * CAP + slot] =                           \
                    make_int2((rl << 17) | (CC), __float_as_int(VV));         \
            else {                                                            \
                int o = atomicAdd(ocnt, 1);                                   \
                if (o < OCAP) ovf[o] = make_int4(bkt, rl, (CC), __float_as_int(VV)); \
            }
            SCAT1(r.x, c.x, v.x)
            SCAT1(r.y, c.y, v.y)
            SCAT1(r.z, c.z, v.z)
            SCAT1(r.w, c.w, v.w)
        } else {
            for (int q = i; q < s1; ++q) {
                int rr = er[q];
                int bkt = rr >> 6, rl = rr & 63;
                int slot = lb[bkt] + atomicAdd(&lh[bkt], 1);
                if (slot < CAP)
                    packed0[(size_t)bkt * CAP + slot] =
                        make_int2((rl << 17) | ec[q], __float_as_int(ev[q]));
                else {
                    int o = atomicAdd(ocnt, 1);
                    if (o < OCAP) ovf[o] = make_int4(bkt, rl, ec[q], __float_as_int(ev[q]));
                }
            }
        }
    }
}

// ---------------------------------------------------------------------------
// Fused regroup + aggregate: one 256-thread block (4 waves) per bucket.
// ---------------------------------------------------------------------------
__global__ __launch_bounds__(256) void k_bagg2(const uint* __restrict__ Hb,
                                               const int* __restrict__ cur,
                                               const int* __restrict__ ocnt,
                                               const int4* __restrict__ ovf,
                                               const int2* __restrict__ packed0,
                                               const float* __restrict__ bias,
                                               float* __restrict__ out, int N) {
    __shared__ int2 srt[CAP];
    __shared__ int lcnt[NPB];
    __shared__ int lpref[NPB];
    __shared__ int lcur[NPB];
    const int t = threadIdx.x;
    const int b = blockIdx.x;
    if (t < NPB) { lcnt[t] = 0; lcur[t] = 0; }
    __syncthreads();

    const int cnt = cur[b * CPAD];
    const int staged = min(cnt, CAP);
    const int2* slab = packed0 + (size_t)b * CAP;

    // phase 1: load + count (entries kept in registers)
    int2 myent[6];
#pragma unroll
    for (int k = 0; k < 6; ++k) {
        const int i = t + k * 256;
        myent[k] = make_int2(0, 0);
        if (i < staged) {
            myent[k] = slab[i];
            atomicAdd(&lcnt[((uint)myent[k].x) >> 17], 1);
        }
    }
    __syncthreads();

    // phase 2: exclusive prefix over 64 counters
    if (t < NPB) {
        int p = 0;
        for (int k = 0; k < t; ++k) p += lcnt[k];
        lpref[t] = p;
    }
    __syncthreads();

    // phase 3: permute into per-node-contiguous LDS buffer
#pragma unroll
    for (int k = 0; k < 6; ++k) {
        const int i = t + k * 256;
        if (i < staged) {
            const int rl = ((uint)myent[k].x) >> 17;
            const int pos = lpref[rl] + atomicAdd(&lcur[rl], 1);
            srt[pos] = make_int2(myent[k].x & 0x1FFFF, myent[k].y);
        }
    }
    __syncthreads();

    // phase 4: aggregate; wave w -> nodes [w*16, w*16+16)
    const int wid = t >> 6, lane = t & 63;
    const int h = lane >> 5, sl = lane & 31;
    const float4 bv = ((const float4*)bias)[sl];
    const int oc = min(*ocnt, OCAP);

    for (int r = wid * 16; r < wid * 16 + 16; ++r) {
        const int node = b * NPB + r;
        if (node >= N) continue;
        const int m = lcnt[r], p0 = lpref[r];
        float4 acc = make_float4(0.f, 0.f, 0.f, 0.f);
        int jj = h;
        for (; jj + 6 < m; jj += 8) {
            const int2 e0 = srt[p0 + jj];
            const int2 e1 = srt[p0 + jj + 2];
            const int2 e2 = srt[p0 + jj + 4];
            const int2 e3 = srt[p0 + jj + 6];
            const uint2 g0 = ((const uint2*)(Hb + (size_t)e0.x * 64))[sl];
            const uint2 g1 = ((const uint2*)(Hb + (size_t)e1.x * 64))[sl];
            const uint2 g2 = ((const uint2*)(Hb + (size_t)e2.x * 64))[sl];
            const uint2 g3 = ((const uint2*)(Hb + (size_t)e3.x * 64))[sl];
            const float v0 = __int_as_float(e0.y);
            const float v1 = __int_as_float(e1.y);
            const float v2 = __int_as_float(e2.y);
            const float v3 = __int_as_float(e3.y);
            acc.x = fmaf(v0, __uint_as_float(g0.x << 16), acc.x);
            acc.y = fmaf(v0, __uint_as_float(g0.x & 0xffff0000u), acc.y);
            acc.z = fmaf(v0, __uint_as_float(g0.y << 16), acc.z);
            acc.w = fmaf(v0, __uint_as_float(g0.y & 0xffff0000u), acc.w);
            acc.x = fmaf(v1, __uint_as_float(g1.x << 16), acc.x);
            acc.y = fmaf(v1, __uint_as_float(g1.x & 0xffff0000u), acc.y);
            acc.z = fmaf(v1, __uint_as_float(g1.y << 16), acc.z);
            acc.w = fmaf(v1, __uint_as_float(g1.y & 0xffff0000u), acc.w);
            acc.x = fmaf(v2, __uint_as_float(g2.x << 16), acc.x);
            acc.y = fmaf(v2, __uint_as_float(g2.x & 0xffff0000u), acc.y);
            acc.z = fmaf(v2, __uint_as_float(g2.y << 16), acc.z);
            acc.w = fmaf(v2, __uint_as_float(g2.y & 0xffff0000u), acc.w);
            acc.x = fmaf(v3, __uint_as_float(g3.x << 16), acc.x);
            acc.y = fmaf(v3, __uint_as_float(g3.x & 0xffff0000u), acc.y);
            acc.z = fmaf(v3, __uint_as_float(g3.y << 16), acc.z);
            acc.w = fmaf(v3, __uint_as_float(g3.y & 0xffff0000u), acc.w);
        }
        for (; jj < m; jj += 2) {
            const int2 e0 = srt[p0 + jj];
            const uint2 g0 = ((const uint2*)(Hb + (size_t)e0.x * 64))[sl];
            const float v0 = __int_as_float(e0.y);
            acc.x = fmaf(v0, __uint_as_float(g0.x << 16), acc.x);
            acc.y = fmaf(v0, __uint_as_float(g0.x & 0xffff0000u), acc.y);
            acc.z = fmaf(v0, __uint_as_float(g0.y << 16), acc.z);
            acc.w = fmaf(v0, __uint_as_float(g0.y & 0xffff0000u), acc.w);
        }
        // overflow spill (normally oc == 0)
        for (int i = 0; i < oc; ++i) {
            const int4 o4 = ovf[i];
            if (o4.x == b && o4.y == r && h == 0) {
                const float v = __int_as_float(o4.w);
                const uint2 g = ((const uint2*)(Hb + (size_t)o4.z * 64))[sl];
                acc.x = fmaf(v, __uint_as_float(g.x << 16), acc.x);
                acc.y = fmaf(v, __uint_as_float(g.x & 0xffff0000u), acc.y);
                acc.z = fmaf(v, __uint_as_float(g.y << 16), acc.z);
                acc.w = fmaf(v, __uint_as_float(g.y & 0xffff0000u), acc.w);
            }
        }
        acc.x += __shfl_xor(acc.x, 32);
        acc.y += __shfl_xor(acc.y, 32);
        acc.z += __shfl_xor(acc.z, 32);
        acc.w += __shfl_xor(acc.w, 32);
        if (h == 0) {
            float4 o;
            o.x = acc.x + bv.x; o.y = acc.y + bv.y;
            o.z = acc.z + bv.z; o.w = acc.w + bv.w;
            o.x = o.x >= 0.f ? o.x : NEG_SLOPE * o.x;
            o.y = o.y >= 0.f ? o.y : NEG_SLOPE * o.y;
            o.z = o.z >= 0.f ? o.z : NEG_SLOPE * o.z;
            o.w = o.w >= 0.f ? o.w : NEG_SLOPE * o.w;
            ((float4*)(out + (size_t)node * DMODEL))[sl] = o;
        }
    }
}

// ---------------------------------------------------------------------------
extern "C" void kernel_launch(void* const* d_in, const int* in_sizes, int n_in,
                              void* d_out, int out_size, void* d_ws, size_t ws_size,
                              hipStream_t stream) {
    const float* X    = (const float*)d_in[0];
    const int*   er   = (const int*)d_in[1];
    const int*   ec   = (const int*)d_in[2];
    const float* ev   = (const float*)d_in[3];
    const float* W    = (const float*)d_in[4];
    const float* bias = (const float*)d_in[5];
    float* out = (float*)d_out;

    const int N = in_sizes[0] / DMODEL;
    const int E = in_sizes[1];
    const int NBK = (N + NPB - 1) / NPB;   // 1563 for N=100000 (<= NBK_MAX)

    // workspace layout (128B-aligned slabs)
    char* ws = (char*)d_ws;
    size_t off = 0;
    auto alloc = [&](size_t bytes) {
        void* p = ws + off;
        off += (bytes + 127) & ~(size_t)127;
        return p;
    };
    ushort_t* H   = (ushort_t*)alloc((size_t)N * DMODEL * sizeof(ushort_t));
    ushort_t* Wt  = (ushort_t*)alloc((size_t)DMODEL * DMODEL * sizeof(ushort_t));
    int* cur      = (int*)alloc(((size_t)NBK * CPAD + 1) * sizeof(int));  // +ocnt
    int* ocnt     = cur + (size_t)NBK * CPAD;
    int4* ovf     = (int4*)alloc((size_t)OCAP * sizeof(int4));
    int2* packed0 = (int2*)alloc((size_t)NBK * CAP * sizeof(int2));
    (void)ws_size;

    const int ztot = NBK * CPAD + 1;

    // 1) pre: Wt transpose + zero cursors
    hipLaunchKernelGGL(k_pre, dim3(64 + (ztot + 255) / 256), dim3(256), 0, stream,
                       W, Wt, cur, ztot);

    // 2) GEMM (LDS-staged, swizzled) and scatter as separate dispatches
    hipLaunchKernelGGL(k_gemm, dim3((N + 63) / 64), dim3(256), 0, stream, X, Wt, H, N);
    const int chunk = ((((E + SBLK - 1) / SBLK) + 3) & ~3);   // multiple of 4
    hipLaunchKernelGGL(k_scat, dim3(SBLK), dim3(1024), 0, stream,
                       er, ec, ev, cur, ocnt, ovf, packed0, E, NBK, chunk);

    // 3) fused regroup + aggregate, one 256-thread block per bucket
    hipLaunchKernelGGL(k_bagg2, dim3(NBK), dim3(256), 0, stream,
                       (const uint*)H, cur, ocnt, ovf, packed0, bias, out, N);
}